// Round 9
// baseline (235.405 us; speedup 1.0000x reference)
//
#include <hip/hip_runtime.h>

// DividedModel: 64 towers of Dense(32,64)+ReLU -> 64x64+ReLU -> 64x64+ReLU -> 64x1.
// R8: big-block occupancy. 1024-thread blocks (16 waves), BPT=32 kept (block =
// 1 tower x 512 rows -- the write/fetch-clean mapping from R7). Each wave runs a
// straight-line 2-tile-chain pass (no loop => no LICM launder needed). Staging
// via prep_kernel image + 21 async global_load_lds chunks. launch_bounds(1024,8)
// caps unified VGPR+AGPR at 256/wave => 2 blocks/CU = 32 waves = 100% target.

typedef float  f32x4 __attribute__((ext_vector_type(4)));
typedef short  bf8   __attribute__((ext_vector_type(8)));
typedef unsigned int uint4v __attribute__((ext_vector_type(4)));

static constexpr int Bsz  = 16384;
static constexpr int Idim = 32;
static constexpr int Odim = 64;
static constexpr int BPT  = 32;                    // blocks per tower (1 tower x 512 rows)

// per-tower LDS image layout (bytes):
//   [0,4096)      ushort Wt0[64*32]   Wt0[h*32 + (i^swz0)]
//   [4096,12288)  ushort Wt1[64*64]   Wt1[h*64 + (S^swz1)]
//   [12288,20480) ushort Wt2[64*64]
//   [20480,20608) ushort w3s[64]      w3s[S]
//   [20608,21376) float  bs[192]      b0|b1|b2
//   [21376,21504) pad
static constexpr int IMG = 21504;                  // 21 chunks x 1024B

#define GLD16(gp, lp) __builtin_amdgcn_global_load_lds( \
    (const __attribute__((address_space(1))) void*)(gp), \
    (__attribute__((address_space(3))) void*)(lp), 16, 0, 0)

__device__ __forceinline__ unsigned short f2bf(float f) {
    unsigned int u = __builtin_bit_cast(unsigned int, f);
    unsigned int r = u + 0x7FFFu + ((u >> 16) & 1u);   // RNE
    return (unsigned short)(r >> 16);
}

__device__ __forceinline__ unsigned cvt_pk(float lo, float hi) {
    unsigned d;
    asm("v_cvt_pk_bf16_f32 %0, %1, %2" : "=v"(d) : "v"(lo), "v"(hi));
    return d;
}

// pi permutation: k-slot S for input-hidden index `in` (0..63).
// in_h(S) = 32*(S>>5) + 16*((S&7)>>2) + 4*((S>>3)&3) + (S&3).
__device__ __forceinline__ int pi_slot(int in) {
    return 32 * (in >> 5) + 8 * ((in >> 2) & 3) + 4 * ((in >> 4) & 1) + (in & 3);
}

// ---------------- prep: build per-tower LDS images in d_ws ----------------
__global__ __launch_bounds__(256) void prep_kernel(
    const float* __restrict__ W0, const float* __restrict__ b0,
    const float* __restrict__ W1, const float* __restrict__ b1,
    const float* __restrict__ W2, const float* __restrict__ b2,
    const float* __restrict__ W3, char* __restrict__ ws)
{
    const int o = blockIdx.x, tid = threadIdx.x;
    char* img = ws + o * IMG;
    unsigned short* Wt0 = (unsigned short*)img;
    unsigned short* Wt1 = (unsigned short*)(img + 4096);
    unsigned short* Wt2 = (unsigned short*)(img + 12288);
    unsigned short* w3s = (unsigned short*)(img + 20480);
    float*          bsf = (float*)(img + 20608);

    for (int f = tid; f < 512; f += 256) {                 // W0: 2048 floats
        f32x4 v = *(const f32x4*)&W0[o * 2048 + f * 4];
        int i  = (f * 4) >> 6;
        int h0 = (f * 4) & 63;
#pragma unroll
        for (int j = 0; j < 4; ++j) {
            int h = h0 + j;
            Wt0[h * 32 + (i ^ ((((h >> 2) ^ h) & 3) << 3))] = f2bf(v[j]);
        }
    }
    for (int f = tid; f < 1024; f += 256) {                // W1/W2: 4096 floats each
        f32x4 v1 = *(const f32x4*)&W1[o * 4096 + f * 4];
        f32x4 v2 = *(const f32x4*)&W2[o * 4096 + f * 4];
        int in = (f * 4) >> 6;
        int h0 = (f * 4) & 63;
        int S  = pi_slot(in);
#pragma unroll
        for (int j = 0; j < 4; ++j) {
            int h = h0 + j;
            int cw = S ^ ((((h >> 2) ^ h) & 7) << 3);
            Wt1[h * 64 + cw] = f2bf(v1[j]);
            Wt2[h * 64 + cw] = f2bf(v2[j]);
        }
    }
    if (tid < 64) {
        w3s[pi_slot(tid)] = f2bf(W3[o * 64 + tid]);
        bsf[tid]       = b0[o * 64 + tid];
        bsf[64 + tid]  = b1[o * 64 + tid];
        bsf[128 + tid] = b2[o * 64 + tid];
    }
}

// ---------------- main: DMA-stage image, one straight-line pass ----------------
__global__ __launch_bounds__(1024, 8) void towers_kernel(
    const float* __restrict__ x, const char* __restrict__ ws,
    const float* __restrict__ b3, float* __restrict__ out)
{
    __shared__ __align__(16) char SH[IMG];

    const int tid  = threadIdx.x;
    const int o    = blockIdx.x / BPT;
    const int slot = blockIdx.x % BPT;
    const int l = tid & 63, w = tid >> 6;    // w: 0..15 waves
    const int c = l & 15,  g = l >> 4;       // c: batch col; g: k-group / D row-group

    // ---- stage the tower image: 21 async 1KB chunks across 16 waves ----
    {
        const char* img = ws + o * IMG;
        GLD16(img + w * 1024 + l * 16, SH + w * 1024);
        if (w < 5)
            GLD16(img + (16 + w) * 1024 + l * 16, SH + (16 + w) * 1024);
    }
    __syncthreads();

    const unsigned short* Wt0 = (const unsigned short*)SH;
    const unsigned short* Wt1 = (const unsigned short*)(SH + 4096);
    const unsigned short* Wt2 = (const unsigned short*)(SH + 12288);
    const unsigned short* w3s = (const unsigned short*)(SH + 20480);
    const float*          bsf = (const float*)(SH + 20608);

    // ---- weight frags (single-use pass; compiler schedules the whole DAG) ----
    bf8 wf0[4], wf1f[4][2], wf2f[4][2];
#pragma unroll
    for (int n = 0; n < 4; ++n) {
        int h = n * 16 + c;
        wf0[n] = *(const bf8*)&Wt0[h * 32 + ((g * 8) ^ ((((h >> 2) ^ h) & 3) << 3))];
        int key = ((h >> 2) ^ h) & 7;
#pragma unroll
        for (int s = 0; s < 2; ++s) {
            int col = (s * 32 + g * 8) ^ (key << 3);
            wf1f[n][s] = *(const bf8*)&Wt1[h * 64 + col];
            wf2f[n][s] = *(const bf8*)&Wt2[h * 64 + col];
        }
    }
    bf8 w3a[2];
    w3a[0] = *(const bf8*)&w3s[g * 8];
    w3a[1] = *(const bf8*)&w3s[32 + g * 8];

    // ---- bias C-frags: element r of chunk n is hidden 16n+4g+r ----
    f32x4 b0f[4], b1f[4], b2f[4];
#pragma unroll
    for (int n = 0; n < 4; ++n) {
        b0f[n] = *(const f32x4*)&bsf[      n * 16 + g * 4];
        b1f[n] = *(const f32x4*)&bsf[ 64 + n * 16 + g * 4];
        b2f[n] = *(const f32x4*)&bsf[128 + n * 16 + g * 4];
    }
    f32x4 c3 = {0.f, 0.f, 0.f, 0.f};
    if (g == 0) c3[0] = b3[o];                // b3 lands on D row 0 only

    // ---- x loads: 2 tiles (rows w*32+{0..15} and +{16..31}) ----
    const float* xp = x + (slot * 512 + w * 32 + c) * Idim + g * 8;
    f32x4 xa0 = *(const f32x4*)(xp);
    f32x4 xb0 = *(const f32x4*)(xp + 4);
    f32x4 xa1 = *(const f32x4*)(xp + 512);    // +16 rows
    f32x4 xb1 = *(const f32x4*)(xp + 516);

    // ---- L0 B-frags ----
    uint4v xd0, xd1;
    xd0.x = cvt_pk(xa0[0], xa0[1]); xd0.y = cvt_pk(xa0[2], xa0[3]);
    xd0.z = cvt_pk(xb0[0], xb0[1]); xd0.w = cvt_pk(xb0[2], xb0[3]);
    xd1.x = cvt_pk(xa1[0], xa1[1]); xd1.y = cvt_pk(xa1[2], xa1[3]);
    xd1.z = cvt_pk(xb1[0], xb1[1]); xd1.w = cvt_pk(xb1[2], xb1[3]);
    bf8 a0_0 = __builtin_bit_cast(bf8, xd0);
    bf8 a0_1 = __builtin_bit_cast(bf8, xd1);

    f32x4 acc0[4], acc1[4];
#pragma unroll
    for (int n = 0; n < 4; ++n) {
        acc0[n] = __builtin_amdgcn_mfma_f32_16x16x32_bf16(wf0[n], a0_0, b0f[n], 0, 0, 0);
        acc1[n] = __builtin_amdgcn_mfma_f32_16x16x32_bf16(wf0[n], a0_1, b0f[n], 0, 0, 0);
    }

    // ---- relu + pack (lane-local thanks to pi staging) ----
    unsigned p0[4][2], p1[4][2];
#pragma unroll
    for (int n = 0; n < 4; ++n) {
        p0[n][0] = cvt_pk(fmaxf(acc0[n][0], 0.f), fmaxf(acc0[n][1], 0.f));
        p0[n][1] = cvt_pk(fmaxf(acc0[n][2], 0.f), fmaxf(acc0[n][3], 0.f));
        p1[n][0] = cvt_pk(fmaxf(acc1[n][0], 0.f), fmaxf(acc1[n][1], 0.f));
        p1[n][1] = cvt_pk(fmaxf(acc1[n][2], 0.f), fmaxf(acc1[n][3], 0.f));
    }
    bf8 Blo0 = __builtin_bit_cast(bf8, uint4v{p0[0][0], p0[0][1], p0[1][0], p0[1][1]});
    bf8 Bhi0 = __builtin_bit_cast(bf8, uint4v{p0[2][0], p0[2][1], p0[3][0], p0[3][1]});
    bf8 Blo1 = __builtin_bit_cast(bf8, uint4v{p1[0][0], p1[0][1], p1[1][0], p1[1][1]});
    bf8 Bhi1 = __builtin_bit_cast(bf8, uint4v{p1[2][0], p1[2][1], p1[3][0], p1[3][1]});

    // ---- L1 ----
#pragma unroll
    for (int n = 0; n < 4; ++n) {
        acc0[n] = __builtin_amdgcn_mfma_f32_16x16x32_bf16(wf1f[n][0], Blo0, b1f[n], 0, 0, 0);
        acc1[n] = __builtin_amdgcn_mfma_f32_16x16x32_bf16(wf1f[n][0], Blo1, b1f[n], 0, 0, 0);
        acc0[n] = __builtin_amdgcn_mfma_f32_16x16x32_bf16(wf1f[n][1], Bhi0, acc0[n], 0, 0, 0);
        acc1[n] = __builtin_amdgcn_mfma_f32_16x16x32_bf16(wf1f[n][1], Bhi1, acc1[n], 0, 0, 0);
    }
#pragma unroll
    for (int n = 0; n < 4; ++n) {
        p0[n][0] = cvt_pk(fmaxf(acc0[n][0], 0.f), fmaxf(acc0[n][1], 0.f));
        p0[n][1] = cvt_pk(fmaxf(acc0[n][2], 0.f), fmaxf(acc0[n][3], 0.f));
        p1[n][0] = cvt_pk(fmaxf(acc1[n][0], 0.f), fmaxf(acc1[n][1], 0.f));
        p1[n][1] = cvt_pk(fmaxf(acc1[n][2], 0.f), fmaxf(acc1[n][3], 0.f));
    }
    Blo0 = __builtin_bit_cast(bf8, uint4v{p0[0][0], p0[0][1], p0[1][0], p0[1][1]});
    Bhi0 = __builtin_bit_cast(bf8, uint4v{p0[2][0], p0[2][1], p0[3][0], p0[3][1]});
    Blo1 = __builtin_bit_cast(bf8, uint4v{p1[0][0], p1[0][1], p1[1][0], p1[1][1]});
    Bhi1 = __builtin_bit_cast(bf8, uint4v{p1[2][0], p1[2][1], p1[3][0], p1[3][1]});

    // ---- L2 ----
#pragma unroll
    for (int n = 0; n < 4; ++n) {
        acc0[n] = __builtin_amdgcn_mfma_f32_16x16x32_bf16(wf2f[n][0], Blo0, b2f[n], 0, 0, 0);
        acc1[n] = __builtin_amdgcn_mfma_f32_16x16x32_bf16(wf2f[n][0], Blo1, b2f[n], 0, 0, 0);
        acc0[n] = __builtin_amdgcn_mfma_f32_16x16x32_bf16(wf2f[n][1], Bhi0, acc0[n], 0, 0, 0);
        acc1[n] = __builtin_amdgcn_mfma_f32_16x16x32_bf16(wf2f[n][1], Bhi1, acc1[n], 0, 0, 0);
    }
#pragma unroll
    for (int n = 0; n < 4; ++n) {
        p0[n][0] = cvt_pk(fmaxf(acc0[n][0], 0.f), fmaxf(acc0[n][1], 0.f));
        p0[n][1] = cvt_pk(fmaxf(acc0[n][2], 0.f), fmaxf(acc0[n][3], 0.f));
        p1[n][0] = cvt_pk(fmaxf(acc1[n][0], 0.f), fmaxf(acc1[n][1], 0.f));
        p1[n][1] = cvt_pk(fmaxf(acc1[n][2], 0.f), fmaxf(acc1[n][3], 0.f));
    }
    Blo0 = __builtin_bit_cast(bf8, uint4v{p0[0][0], p0[0][1], p0[1][0], p0[1][1]});
    Bhi0 = __builtin_bit_cast(bf8, uint4v{p0[2][0], p0[2][1], p0[3][0], p0[3][1]});
    Blo1 = __builtin_bit_cast(bf8, uint4v{p1[0][0], p1[0][1], p1[1][0], p1[1][1]});
    Bhi1 = __builtin_bit_cast(bf8, uint4v{p1[2][0], p1[2][1], p1[3][0], p1[3][1]});

    // ---- L3: 2 MFMAs per tile vs broadcast w3 rows; row 0 = dot + b3 ----
    f32x4 acc3_0, acc3_1;
    acc3_0 = __builtin_amdgcn_mfma_f32_16x16x32_bf16(w3a[0], Blo0, c3,     0, 0, 0);
    acc3_1 = __builtin_amdgcn_mfma_f32_16x16x32_bf16(w3a[0], Blo1, c3,     0, 0, 0);
    acc3_0 = __builtin_amdgcn_mfma_f32_16x16x32_bf16(w3a[1], Bhi0, acc3_0, 0, 0, 0);
    acc3_1 = __builtin_amdgcn_mfma_f32_16x16x32_bf16(w3a[1], Bhi1, acc3_1, 0, 0, 0);

    if (g == 0) {
        float* op = out + (slot * 512 + w * 32 + c) * Odim + o;
        op[0]         = acc3_0[0];
        op[16 * Odim] = acc3_1[0];
    }
}

extern "C" void kernel_launch(void* const* d_in, const int* in_sizes, int n_in,
                              void* d_out, int out_size, void* d_ws, size_t ws_size,
                              hipStream_t stream) {
    const float* x  = (const float*)d_in[0];
    const float* W0 = (const float*)d_in[1];
    const float* b0 = (const float*)d_in[2];
    const float* W1 = (const float*)d_in[3];
    const float* b1 = (const float*)d_in[4];
    const float* W2 = (const float*)d_in[5];
    const float* b2 = (const float*)d_in[6];
    const float* W3 = (const float*)d_in[7];
    const float* b3 = (const float*)d_in[8];
    float* out = (float*)d_out;
    char* ws = (char*)d_ws;   // needs 64*21504 = 1.38 MB

    prep_kernel<<<dim3(Odim), dim3(256), 0, stream>>>(W0, b0, W1, b1, W2, b2, W3, ws);
    towers_kernel<<<dim3(Odim * BPT), dim3(1024), 0, stream>>>(x, ws, b3, out);
}

// Round 11
// 38.907 us; speedup vs baseline: 6.0505x; 6.0505x over previous
//
#include <hip/hip_runtime.h>

// DividedModel: 64 towers of Dense(32,64)+ReLU -> 64x64+ReLU -> 64x64+ReLU -> 64x1.
// R10 (=R9 fixed): R7 structure (prep-kernel weight images + global_load_lds
// staging, 256thr, BPT=32, 2-tile ILP, pi-trick, bias-in-C, L3-as-MFMA) with
// bf16 -> f16: same MFMA rate, packed ReLU via v_pk_max_f16 inline asm
// (ROCm header __hmax2 overload fails to resolve), input cvt via cvt_pkrtz.

typedef float  f32x4 __attribute__((ext_vector_type(4)));
typedef _Float16 h8  __attribute__((ext_vector_type(8)));
typedef unsigned int uint4v __attribute__((ext_vector_type(4)));

static constexpr int Bsz  = 16384;
static constexpr int Idim = 32;
static constexpr int Odim = 64;
static constexpr int BPT  = 32;                    // blocks per tower
static constexpr int ROWTILES = (Bsz / 64) / BPT;  // 8 tiles of 64 rows per block

// per-tower LDS image layout (bytes):
//   [0,4096)      ushort Wt0[64*32]   Wt0[h*32 + (i^swz0)]
//   [4096,12288)  ushort Wt1[64*64]   Wt1[h*64 + (S^swz1)]
//   [12288,20480) ushort Wt2[64*64]
//   [20480,20608) ushort w3s[64]      w3s[S]
//   [20608,21376) float  bs[192]      b0|b1|b2
//   [21376,21504) pad
static constexpr int IMG = 21504;                  // 21 chunks x 1024B

#define GLD16(gp, lp) __builtin_amdgcn_global_load_lds( \
    (const __attribute__((address_space(1))) void*)(gp), \
    (__attribute__((address_space(3))) void*)(lp), 16, 0, 0)

__device__ __forceinline__ unsigned short f2h(float f) {   // RNE f32->f16 (staging)
    _Float16 h = (_Float16)f;
    return __builtin_bit_cast(unsigned short, h);
}

__device__ __forceinline__ unsigned cvt_relu_pk(float lo, float hi) {
    // pack 2 f32 -> 2 f16 (RTZ), then packed ReLU: one v_pk_max_f16
    unsigned v = __builtin_bit_cast(unsigned, __builtin_amdgcn_cvt_pkrtz(lo, hi));
    unsigned r;
    asm("v_pk_max_f16 %0, %1, 0" : "=v"(r) : "v"(v));
    return r;
}

__device__ __forceinline__ unsigned cvt_pk2(float lo, float hi) {  // no relu (inputs)
    return __builtin_bit_cast(unsigned, __builtin_amdgcn_cvt_pkrtz(lo, hi));
}

// pi permutation: k-slot S for input-hidden index `in` (0..63).
// in_h(S) = 32*(S>>5) + 16*((S&7)>>2) + 4*((S>>3)&3) + (S&3).
__device__ __forceinline__ int pi_slot(int in) {
    return 32 * (in >> 5) + 8 * ((in >> 2) & 3) + 4 * ((in >> 4) & 1) + (in & 3);
}

// ---------------- prep: build per-tower LDS images in d_ws (one pass) ----------------
__global__ __launch_bounds__(1024) void prep_kernel(
    const float* __restrict__ W0, const float* __restrict__ b0,
    const float* __restrict__ W1, const float* __restrict__ b1,
    const float* __restrict__ W2, const float* __restrict__ b2,
    const float* __restrict__ W3, char* __restrict__ ws)
{
    const int o = blockIdx.x, tid = threadIdx.x;
    char* img = ws + o * IMG;
    unsigned short* Wt0 = (unsigned short*)img;
    unsigned short* Wt1 = (unsigned short*)(img + 4096);
    unsigned short* Wt2 = (unsigned short*)(img + 12288);
    unsigned short* w3s = (unsigned short*)(img + 20480);
    float*          bsf = (float*)(img + 20608);

    if (tid < 512) {                                      // W0: 2048 floats
        f32x4 v = *(const f32x4*)&W0[o * 2048 + tid * 4];
        int i  = (tid * 4) >> 6;
        int h0 = (tid * 4) & 63;
#pragma unroll
        for (int j = 0; j < 4; ++j) {
            int h = h0 + j;
            Wt0[h * 32 + (i ^ ((((h >> 2) ^ h) & 3) << 3))] = f2h(v[j]);
        }
    }
    {                                                     // W1/W2: 4096 floats each
        f32x4 v1 = *(const f32x4*)&W1[o * 4096 + tid * 4];
        f32x4 v2 = *(const f32x4*)&W2[o * 4096 + tid * 4];
        int in = (tid * 4) >> 6;
        int h0 = (tid * 4) & 63;
        int S  = pi_slot(in);
#pragma unroll
        for (int j = 0; j < 4; ++j) {
            int h = h0 + j;
            int cw = S ^ ((((h >> 2) ^ h) & 7) << 3);
            Wt1[h * 64 + cw] = f2h(v1[j]);
            Wt2[h * 64 + cw] = f2h(v2[j]);
        }
    }
    if (tid < 64) {
        w3s[pi_slot(tid)] = f2h(W3[o * 64 + tid]);
        bsf[tid]       = b0[o * 64 + tid];
        bsf[64 + tid]  = b1[o * 64 + tid];
        bsf[128 + tid] = b2[o * 64 + tid];
    }
}

// ---------------- main: DMA-stage image, then 2-tile-ILP loop ----------------
__global__ __launch_bounds__(256, 2) void towers_kernel(
    const float* __restrict__ x, const char* __restrict__ ws,
    const float* __restrict__ b3, float* __restrict__ out)
{
    __shared__ __align__(16) char SH[IMG];

    const int tid  = threadIdx.x;
    const int o    = blockIdx.x / BPT;
    const int slot = blockIdx.x % BPT;
    const int l = tid & 63, w = tid >> 6;
    const int c = l & 15,  g = l >> 4;   // c: batch col; g: k-group / D row-group

    // ---- stage the tower image: 21 async 1KB chunks, waves round-robin ----
    {
        const char* img = ws + o * IMG;
#pragma unroll
        for (int ch = 0; ch < 6; ++ch) {
            int k = ch * 4 + w;
            if (k < 21)
                GLD16(img + k * 1024 + l * 16, SH + k * 1024);
        }
    }
    __syncthreads();

    const unsigned short* Wt0 = (const unsigned short*)SH;
    const unsigned short* Wt1 = (const unsigned short*)(SH + 4096);
    const unsigned short* w3s = (const unsigned short*)(SH + 20480);
    const float*          bsf = (const float*)(SH + 20608);

    // ---- persistent weight frags: W0 (16), W1 (32), w3 (8) ----
    h8 wf0[4], wf1f[4][2];
#pragma unroll
    for (int n = 0; n < 4; ++n) {
        int h = n * 16 + c;
        wf0[n] = *(const h8*)&Wt0[h * 32 + ((g * 8) ^ ((((h >> 2) ^ h) & 3) << 3))];
        int key = ((h >> 2) ^ h) & 7;
#pragma unroll
        for (int s = 0; s < 2; ++s)
            wf1f[n][s] = *(const h8*)&Wt1[h * 64 + ((s * 32 + g * 8) ^ (key << 3))];
    }
    h8 w3a[2];
    w3a[0] = *(const h8*)&w3s[g * 8];
    w3a[1] = *(const h8*)&w3s[32 + g * 8];

    // ---- W2 frag BYTE offsets into SH, precomputed (laundered per use) ----
    int off2[4][2];
#pragma unroll
    for (int n = 0; n < 4; ++n) {
        int h = n * 16 + c;
        int key = ((h >> 2) ^ h) & 7;
#pragma unroll
        for (int s = 0; s < 2; ++s)
            off2[n][s] = 12288 + 2 * (h * 64 + ((s * 32 + g * 8) ^ (key << 3)));
    }

    // ---- bias C-frags: element r of chunk n is hidden 16n+4g+r ----
    f32x4 b0f[4], b1f[4], b2f[4];
#pragma unroll
    for (int n = 0; n < 4; ++n) {
        b0f[n] = *(const f32x4*)&bsf[      n * 16 + g * 4];
        b1f[n] = *(const f32x4*)&bsf[ 64 + n * 16 + g * 4];
        b2f[n] = *(const f32x4*)&bsf[128 + n * 16 + g * 4];
    }
    f32x4 c3 = {0.f, 0.f, 0.f, 0.f};
    if (g == 0) c3[0] = b3[o];                // b3 lands on D row 0 only

    const float* xbase = x + (slot * ROWTILES * 64 + w * 16 + c) * Idim + g * 8;
    float* obase = out + (slot * ROWTILES * 64 + w * 16 + c) * Odim + o;

    f32x4 nxa0 = *(const f32x4*)(xbase);
    f32x4 nxb0 = *(const f32x4*)(xbase + 4);
    f32x4 nxa1 = *(const f32x4*)(xbase + 2048);
    f32x4 nxb1 = *(const f32x4*)(xbase + 2052);

    for (int tt = 0; tt < ROWTILES; tt += 2) {
        f32x4 xa0 = nxa0, xb0 = nxb0, xa1 = nxa1, xb1 = nxb1;
        if (tt + 2 < ROWTILES) {              // prefetch next pair
            const float* np = xbase + (tt + 2) * 2048;
            nxa0 = *(const f32x4*)(np);
            nxb0 = *(const f32x4*)(np + 4);
            nxa1 = *(const f32x4*)(np + 2048);
            nxb1 = *(const f32x4*)(np + 2052);
        }

        // ---- L0 B-frags from x (cvt only, no relu) ----
        uint4v xd0, xd1;
        xd0.x = cvt_pk2(xa0[0], xa0[1]); xd0.y = cvt_pk2(xa0[2], xa0[3]);
        xd0.z = cvt_pk2(xb0[0], xb0[1]); xd0.w = cvt_pk2(xb0[2], xb0[3]);
        xd1.x = cvt_pk2(xa1[0], xa1[1]); xd1.y = cvt_pk2(xa1[2], xa1[3]);
        xd1.z = cvt_pk2(xb1[0], xb1[1]); xd1.w = cvt_pk2(xb1[2], xb1[3]);
        h8 a0_0 = __builtin_bit_cast(h8, xd0);
        h8 a0_1 = __builtin_bit_cast(h8, xd1);

        f32x4 acc0[4], acc1[4];
#pragma unroll
        for (int n = 0; n < 4; ++n) {
            acc0[n] = __builtin_amdgcn_mfma_f32_16x16x32_f16(wf0[n], a0_0, b0f[n], 0, 0, 0);
            acc1[n] = __builtin_amdgcn_mfma_f32_16x16x32_f16(wf0[n], a0_1, b0f[n], 0, 0, 0);
        }

        // ---- cvt+relu pack (lane-local thanks to pi staging) ----
        unsigned p0[4][2], p1[4][2];
#pragma unroll
        for (int n = 0; n < 4; ++n) {
            p0[n][0] = cvt_relu_pk(acc0[n][0], acc0[n][1]);
            p0[n][1] = cvt_relu_pk(acc0[n][2], acc0[n][3]);
            p1[n][0] = cvt_relu_pk(acc1[n][0], acc1[n][1]);
            p1[n][1] = cvt_relu_pk(acc1[n][2], acc1[n][3]);
        }
        h8 Blo0 = __builtin_bit_cast(h8, uint4v{p0[0][0], p0[0][1], p0[1][0], p0[1][1]});
        h8 Bhi0 = __builtin_bit_cast(h8, uint4v{p0[2][0], p0[2][1], p0[3][0], p0[3][1]});
        h8 Blo1 = __builtin_bit_cast(h8, uint4v{p1[0][0], p1[0][1], p1[1][0], p1[1][1]});
        h8 Bhi1 = __builtin_bit_cast(h8, uint4v{p1[2][0], p1[2][1], p1[3][0], p1[3][1]});

        // ---- L1 (weights in regs) ----
#pragma unroll
        for (int n = 0; n < 4; ++n) {
            acc0[n] = __builtin_amdgcn_mfma_f32_16x16x32_f16(wf1f[n][0], Blo0, b1f[n], 0, 0, 0);
            acc1[n] = __builtin_amdgcn_mfma_f32_16x16x32_f16(wf1f[n][0], Blo1, b1f[n], 0, 0, 0);
            acc0[n] = __builtin_amdgcn_mfma_f32_16x16x32_f16(wf1f[n][1], Bhi0, acc0[n], 0, 0, 0);
            acc1[n] = __builtin_amdgcn_mfma_f32_16x16x32_f16(wf1f[n][1], Bhi1, acc1[n], 0, 0, 0);
        }
#pragma unroll
        for (int n = 0; n < 4; ++n) {
            p0[n][0] = cvt_relu_pk(acc0[n][0], acc0[n][1]);
            p0[n][1] = cvt_relu_pk(acc0[n][2], acc0[n][3]);
            p1[n][0] = cvt_relu_pk(acc1[n][0], acc1[n][1]);
            p1[n][1] = cvt_relu_pk(acc1[n][2], acc1[n][3]);
        }
        Blo0 = __builtin_bit_cast(h8, uint4v{p0[0][0], p0[0][1], p0[1][0], p0[1][1]});
        Bhi0 = __builtin_bit_cast(h8, uint4v{p0[2][0], p0[2][1], p0[3][0], p0[3][1]});
        Blo1 = __builtin_bit_cast(h8, uint4v{p1[0][0], p1[0][1], p1[1][0], p1[1][1]});
        Bhi1 = __builtin_bit_cast(h8, uint4v{p1[2][0], p1[2][1], p1[3][0], p1[3][1]});

        // ---- L2: W2 frags from LDS (shared by both chains; laundered offsets) ----
        {
            const char* base = (const char*)SH;
            h8 w2[4];
#pragma unroll
            for (int n = 0; n < 4; ++n) {
                int a = off2[n][0];
                asm("" : "+v"(a));             // 1 v_mov; blocks LICM of the read
                w2[n] = *(const h8*)(base + a);
            }
#pragma unroll
            for (int n = 0; n < 4; ++n) {
                acc0[n] = __builtin_amdgcn_mfma_f32_16x16x32_f16(w2[n], Blo0, b2f[n], 0, 0, 0);
                acc1[n] = __builtin_amdgcn_mfma_f32_16x16x32_f16(w2[n], Blo1, b2f[n], 0, 0, 0);
            }
#pragma unroll
            for (int n = 0; n < 4; ++n) {
                int a = off2[n][1];
                asm("" : "+v"(a));
                w2[n] = *(const h8*)(base + a);
            }
#pragma unroll
            for (int n = 0; n < 4; ++n) {
                acc0[n] = __builtin_amdgcn_mfma_f32_16x16x32_f16(w2[n], Bhi0, acc0[n], 0, 0, 0);
                acc1[n] = __builtin_amdgcn_mfma_f32_16x16x32_f16(w2[n], Bhi1, acc1[n], 0, 0, 0);
            }
        }
#pragma unroll
        for (int n = 0; n < 4; ++n) {
            p0[n][0] = cvt_relu_pk(acc0[n][0], acc0[n][1]);
            p0[n][1] = cvt_relu_pk(acc0[n][2], acc0[n][3]);
            p1[n][0] = cvt_relu_pk(acc1[n][0], acc1[n][1]);
            p1[n][1] = cvt_relu_pk(acc1[n][2], acc1[n][3]);
        }
        Blo0 = __builtin_bit_cast(h8, uint4v{p0[0][0], p0[0][1], p0[1][0], p0[1][1]});
        Bhi0 = __builtin_bit_cast(h8, uint4v{p0[2][0], p0[2][1], p0[3][0], p0[3][1]});
        Blo1 = __builtin_bit_cast(h8, uint4v{p1[0][0], p1[0][1], p1[1][0], p1[1][1]});
        Bhi1 = __builtin_bit_cast(h8, uint4v{p1[2][0], p1[2][1], p1[3][0], p1[3][1]});

        // ---- L3: 2 MFMAs per tile vs broadcast w3 rows; row 0 = dot + b3 ----
        f32x4 acc3_0, acc3_1;
        acc3_0 = __builtin_amdgcn_mfma_f32_16x16x32_f16(w3a[0], Blo0, c3,     0, 0, 0);
        acc3_1 = __builtin_amdgcn_mfma_f32_16x16x32_f16(w3a[0], Blo1, c3,     0, 0, 0);
        acc3_0 = __builtin_amdgcn_mfma_f32_16x16x32_f16(w3a[1], Bhi0, acc3_0, 0, 0, 0);
        acc3_1 = __builtin_amdgcn_mfma_f32_16x16x32_f16(w3a[1], Bhi1, acc3_1, 0, 0, 0);

        if (g == 0) {
            obase[(tt)     * 64 * Odim] = acc3_0[0];
            obase[(tt + 1) * 64 * Odim] = acc3_1[0];
        }
    }
}

extern "C" void kernel_launch(void* const* d_in, const int* in_sizes, int n_in,
                              void* d_out, int out_size, void* d_ws, size_t ws_size,
                              hipStream_t stream) {
    const float* x  = (const float*)d_in[0];
    const float* W0 = (const float*)d_in[1];
    const float* b0 = (const float*)d_in[2];
    const float* W1 = (const float*)d_in[3];
    const float* b1 = (const float*)d_in[4];
    const float* W2 = (const float*)d_in[5];
    const float* b2 = (const float*)d_in[6];
    const float* W3 = (const float*)d_in[7];
    const float* b3 = (const float*)d_in[8];
    float* out = (float*)d_out;
    char* ws = (char*)d_ws;   // needs 64*21504 = 1.38 MB

    prep_kernel<<<dim3(Odim), dim3(1024), 0, stream>>>(W0, b0, W1, b1, W2, b2, W3, ws);
    towers_kernel<<<dim3(Odim * BPT), dim3(256), 0, stream>>>(x, ws, b3, out);
}

// Round 12
// 34.013 us; speedup vs baseline: 6.9210x; 1.1439x over previous
//
#include <hip/hip_runtime.h>

// DividedModel: 64 towers of Dense(32,64)+ReLU -> 64x64+ReLU -> 64x64+ReLU -> 64x1.
// R11: R10 (f16, prep-image + global_load_lds staging, 2-tile ILP, pi-trick,
// bias-in-C, L3-as-MFMA) with BPT 32 -> 16: 1024 blocks, 16 tiles/block --
// halves the number of sequential CU-rounds and thus the replicated per-block
// fixed cost (staging drain + frag hoist). First x prefetch issued BEFORE the
// staging DMA so x HBM latency hides under the image load (same vmcnt drain).

typedef float  f32x4 __attribute__((ext_vector_type(4)));
typedef _Float16 h8  __attribute__((ext_vector_type(8)));
typedef unsigned int uint4v __attribute__((ext_vector_type(4)));

static constexpr int Bsz  = 16384;
static constexpr int Idim = 32;
static constexpr int Odim = 64;
static constexpr int BPT  = 16;                    // blocks per tower
static constexpr int ROWTILES = (Bsz / 64) / BPT;  // 16 tiles of 64 rows per block

// per-tower LDS image layout (bytes):
//   [0,4096)      ushort Wt0[64*32]   Wt0[h*32 + (i^swz0)]
//   [4096,12288)  ushort Wt1[64*64]   Wt1[h*64 + (S^swz1)]
//   [12288,20480) ushort Wt2[64*64]
//   [20480,20608) ushort w3s[64]      w3s[S]
//   [20608,21376) float  bs[192]      b0|b1|b2
//   [21376,21504) pad
static constexpr int IMG = 21504;                  // 21 chunks x 1024B

#define GLD16(gp, lp) __builtin_amdgcn_global_load_lds( \
    (const __attribute__((address_space(1))) void*)(gp), \
    (__attribute__((address_space(3))) void*)(lp), 16, 0, 0)

__device__ __forceinline__ unsigned short f2h(float f) {   // RNE f32->f16 (staging)
    _Float16 h = (_Float16)f;
    return __builtin_bit_cast(unsigned short, h);
}

__device__ __forceinline__ unsigned cvt_relu_pk(float lo, float hi) {
    // pack 2 f32 -> 2 f16 (RTZ), then packed ReLU: one v_pk_max_f16
    unsigned v = __builtin_bit_cast(unsigned, __builtin_amdgcn_cvt_pkrtz(lo, hi));
    unsigned r;
    asm("v_pk_max_f16 %0, %1, 0" : "=v"(r) : "v"(v));
    return r;
}

__device__ __forceinline__ unsigned cvt_pk2(float lo, float hi) {  // no relu (inputs)
    return __builtin_bit_cast(unsigned, __builtin_amdgcn_cvt_pkrtz(lo, hi));
}

// pi permutation: k-slot S for input-hidden index `in` (0..63).
// in_h(S) = 32*(S>>5) + 16*((S&7)>>2) + 4*((S>>3)&3) + (S&3).
__device__ __forceinline__ int pi_slot(int in) {
    return 32 * (in >> 5) + 8 * ((in >> 2) & 3) + 4 * ((in >> 4) & 1) + (in & 3);
}

// ---------------- prep: build per-tower LDS images in d_ws (one pass) ----------------
__global__ __launch_bounds__(1024) void prep_kernel(
    const float* __restrict__ W0, const float* __restrict__ b0,
    const float* __restrict__ W1, const float* __restrict__ b1,
    const float* __restrict__ W2, const float* __restrict__ b2,
    const float* __restrict__ W3, char* __restrict__ ws)
{
    const int o = blockIdx.x, tid = threadIdx.x;
    char* img = ws + o * IMG;
    unsigned short* Wt0 = (unsigned short*)img;
    unsigned short* Wt1 = (unsigned short*)(img + 4096);
    unsigned short* Wt2 = (unsigned short*)(img + 12288);
    unsigned short* w3s = (unsigned short*)(img + 20480);
    float*          bsf = (float*)(img + 20608);

    if (tid < 512) {                                      // W0: 2048 floats
        f32x4 v = *(const f32x4*)&W0[o * 2048 + tid * 4];
        int i  = (tid * 4) >> 6;
        int h0 = (tid * 4) & 63;
#pragma unroll
        for (int j = 0; j < 4; ++j) {
            int h = h0 + j;
            Wt0[h * 32 + (i ^ ((((h >> 2) ^ h) & 3) << 3))] = f2h(v[j]);
        }
    }
    {                                                     // W1/W2: 4096 floats each
        f32x4 v1 = *(const f32x4*)&W1[o * 4096 + tid * 4];
        f32x4 v2 = *(const f32x4*)&W2[o * 4096 + tid * 4];
        int in = (tid * 4) >> 6;
        int h0 = (tid * 4) & 63;
        int S  = pi_slot(in);
#pragma unroll
        for (int j = 0; j < 4; ++j) {
            int h = h0 + j;
            int cw = S ^ ((((h >> 2) ^ h) & 7) << 3);
            Wt1[h * 64 + cw] = f2h(v1[j]);
            Wt2[h * 64 + cw] = f2h(v2[j]);
        }
    }
    if (tid < 64) {
        w3s[pi_slot(tid)] = f2h(W3[o * 64 + tid]);
        bsf[tid]       = b0[o * 64 + tid];
        bsf[64 + tid]  = b1[o * 64 + tid];
        bsf[128 + tid] = b2[o * 64 + tid];
    }
}

// ---------------- main: DMA-stage image, then 2-tile-ILP loop ----------------
__global__ __launch_bounds__(256, 2) void towers_kernel(
    const float* __restrict__ x, const char* __restrict__ ws,
    const float* __restrict__ b3, float* __restrict__ out)
{
    __shared__ __align__(16) char SH[IMG];

    const int tid  = threadIdx.x;
    const int o    = blockIdx.x / BPT;
    const int slot = blockIdx.x % BPT;
    const int l = tid & 63, w = tid >> 6;
    const int c = l & 15,  g = l >> 4;   // c: batch col; g: k-group / D row-group

    // ---- first x prefetch BEFORE staging: overlaps with image DMA ----
    const float* xbase = x + (slot * ROWTILES * 64 + w * 16 + c) * Idim + g * 8;
    f32x4 nxa0 = *(const f32x4*)(xbase);
    f32x4 nxb0 = *(const f32x4*)(xbase + 4);
    f32x4 nxa1 = *(const f32x4*)(xbase + 2048);
    f32x4 nxb1 = *(const f32x4*)(xbase + 2052);

    // ---- stage the tower image: 21 async 1KB chunks, waves round-robin ----
    {
        const char* img = ws + o * IMG;
#pragma unroll
        for (int ch = 0; ch < 6; ++ch) {
            int k = ch * 4 + w;
            if (k < 21)
                GLD16(img + k * 1024 + l * 16, SH + k * 1024);
        }
    }
    __syncthreads();

    const unsigned short* Wt0 = (const unsigned short*)SH;
    const unsigned short* Wt1 = (const unsigned short*)(SH + 4096);
    const unsigned short* w3s = (const unsigned short*)(SH + 20480);
    const float*          bsf = (const float*)(SH + 20608);

    // ---- persistent weight frags: W0 (16), W1 (32), w3 (8) ----
    h8 wf0[4], wf1f[4][2];
#pragma unroll
    for (int n = 0; n < 4; ++n) {
        int h = n * 16 + c;
        wf0[n] = *(const h8*)&Wt0[h * 32 + ((g * 8) ^ ((((h >> 2) ^ h) & 3) << 3))];
        int key = ((h >> 2) ^ h) & 7;
#pragma unroll
        for (int s = 0; s < 2; ++s)
            wf1f[n][s] = *(const h8*)&Wt1[h * 64 + ((s * 32 + g * 8) ^ (key << 3))];
    }
    h8 w3a[2];
    w3a[0] = *(const h8*)&w3s[g * 8];
    w3a[1] = *(const h8*)&w3s[32 + g * 8];

    // ---- W2 frag BYTE offsets into SH, precomputed (laundered per use) ----
    int off2[4][2];
#pragma unroll
    for (int n = 0; n < 4; ++n) {
        int h = n * 16 + c;
        int key = ((h >> 2) ^ h) & 7;
#pragma unroll
        for (int s = 0; s < 2; ++s)
            off2[n][s] = 12288 + 2 * (h * 64 + ((s * 32 + g * 8) ^ (key << 3)));
    }

    // ---- bias C-frags: element r of chunk n is hidden 16n+4g+r ----
    f32x4 b0f[4], b1f[4], b2f[4];
#pragma unroll
    for (int n = 0; n < 4; ++n) {
        b0f[n] = *(const f32x4*)&bsf[      n * 16 + g * 4];
        b1f[n] = *(const f32x4*)&bsf[ 64 + n * 16 + g * 4];
        b2f[n] = *(const f32x4*)&bsf[128 + n * 16 + g * 4];
    }
    f32x4 c3 = {0.f, 0.f, 0.f, 0.f};
    if (g == 0) c3[0] = b3[o];                // b3 lands on D row 0 only

    float* obase = out + (slot * ROWTILES * 64 + w * 16 + c) * Odim + o;

    for (int tt = 0; tt < ROWTILES; tt += 2) {
        f32x4 xa0 = nxa0, xb0 = nxb0, xa1 = nxa1, xb1 = nxb1;
        if (tt + 2 < ROWTILES) {              // prefetch next pair
            const float* np = xbase + (tt + 2) * 2048;
            nxa0 = *(const f32x4*)(np);
            nxb0 = *(const f32x4*)(np + 4);
            nxa1 = *(const f32x4*)(np + 2048);
            nxb1 = *(const f32x4*)(np + 2052);
        }

        // ---- L0 B-frags from x (cvt only, no relu) ----
        uint4v xd0, xd1;
        xd0.x = cvt_pk2(xa0[0], xa0[1]); xd0.y = cvt_pk2(xa0[2], xa0[3]);
        xd0.z = cvt_pk2(xb0[0], xb0[1]); xd0.w = cvt_pk2(xb0[2], xb0[3]);
        xd1.x = cvt_pk2(xa1[0], xa1[1]); xd1.y = cvt_pk2(xa1[2], xa1[3]);
        xd1.z = cvt_pk2(xb1[0], xb1[1]); xd1.w = cvt_pk2(xb1[2], xb1[3]);
        h8 a0_0 = __builtin_bit_cast(h8, xd0);
        h8 a0_1 = __builtin_bit_cast(h8, xd1);

        f32x4 acc0[4], acc1[4];
#pragma unroll
        for (int n = 0; n < 4; ++n) {
            acc0[n] = __builtin_amdgcn_mfma_f32_16x16x32_f16(wf0[n], a0_0, b0f[n], 0, 0, 0);
            acc1[n] = __builtin_amdgcn_mfma_f32_16x16x32_f16(wf0[n], a0_1, b0f[n], 0, 0, 0);
        }

        // ---- cvt+relu pack (lane-local thanks to pi staging) ----
        unsigned p0[4][2], p1[4][2];
#pragma unroll
        for (int n = 0; n < 4; ++n) {
            p0[n][0] = cvt_relu_pk(acc0[n][0], acc0[n][1]);
            p0[n][1] = cvt_relu_pk(acc0[n][2], acc0[n][3]);
            p1[n][0] = cvt_relu_pk(acc1[n][0], acc1[n][1]);
            p1[n][1] = cvt_relu_pk(acc1[n][2], acc1[n][3]);
        }
        h8 Blo0 = __builtin_bit_cast(h8, uint4v{p0[0][0], p0[0][1], p0[1][0], p0[1][1]});
        h8 Bhi0 = __builtin_bit_cast(h8, uint4v{p0[2][0], p0[2][1], p0[3][0], p0[3][1]});
        h8 Blo1 = __builtin_bit_cast(h8, uint4v{p1[0][0], p1[0][1], p1[1][0], p1[1][1]});
        h8 Bhi1 = __builtin_bit_cast(h8, uint4v{p1[2][0], p1[2][1], p1[3][0], p1[3][1]});

        // ---- L1 (weights in regs) ----
#pragma unroll
        for (int n = 0; n < 4; ++n) {
            acc0[n] = __builtin_amdgcn_mfma_f32_16x16x32_f16(wf1f[n][0], Blo0, b1f[n], 0, 0, 0);
            acc1[n] = __builtin_amdgcn_mfma_f32_16x16x32_f16(wf1f[n][0], Blo1, b1f[n], 0, 0, 0);
            acc0[n] = __builtin_amdgcn_mfma_f32_16x16x32_f16(wf1f[n][1], Bhi0, acc0[n], 0, 0, 0);
            acc1[n] = __builtin_amdgcn_mfma_f32_16x16x32_f16(wf1f[n][1], Bhi1, acc1[n], 0, 0, 0);
        }
#pragma unroll
        for (int n = 0; n < 4; ++n) {
            p0[n][0] = cvt_relu_pk(acc0[n][0], acc0[n][1]);
            p0[n][1] = cvt_relu_pk(acc0[n][2], acc0[n][3]);
            p1[n][0] = cvt_relu_pk(acc1[n][0], acc1[n][1]);
            p1[n][1] = cvt_relu_pk(acc1[n][2], acc1[n][3]);
        }
        Blo0 = __builtin_bit_cast(h8, uint4v{p0[0][0], p0[0][1], p0[1][0], p0[1][1]});
        Bhi0 = __builtin_bit_cast(h8, uint4v{p0[2][0], p0[2][1], p0[3][0], p0[3][1]});
        Blo1 = __builtin_bit_cast(h8, uint4v{p1[0][0], p1[0][1], p1[1][0], p1[1][1]});
        Bhi1 = __builtin_bit_cast(h8, uint4v{p1[2][0], p1[2][1], p1[3][0], p1[3][1]});

        // ---- L2: W2 frags from LDS (shared by both chains; laundered offsets) ----
        {
            const char* base = (const char*)SH;
            h8 w2[4];
#pragma unroll
            for (int n = 0; n < 4; ++n) {
                int a = off2[n][0];
                asm("" : "+v"(a));             // 1 v_mov; blocks LICM of the read
                w2[n] = *(const h8*)(base + a);
            }
#pragma unroll
            for (int n = 0; n < 4; ++n) {
                acc0[n] = __builtin_amdgcn_mfma_f32_16x16x32_f16(w2[n], Blo0, b2f[n], 0, 0, 0);
                acc1[n] = __builtin_amdgcn_mfma_f32_16x16x32_f16(w2[n], Blo1, b2f[n], 0, 0, 0);
            }
#pragma unroll
            for (int n = 0; n < 4; ++n) {
                int a = off2[n][1];
                asm("" : "+v"(a));
                w2[n] = *(const h8*)(base + a);
            }
#pragma unroll
            for (int n = 0; n < 4; ++n) {
                acc0[n] = __builtin_amdgcn_mfma_f32_16x16x32_f16(w2[n], Bhi0, acc0[n], 0, 0, 0);
                acc1[n] = __builtin_amdgcn_mfma_f32_16x16x32_f16(w2[n], Bhi1, acc1[n], 0, 0, 0);
            }
        }
#pragma unroll
        for (int n = 0; n < 4; ++n) {
            p0[n][0] = cvt_relu_pk(acc0[n][0], acc0[n][1]);
            p0[n][1] = cvt_relu_pk(acc0[n][2], acc0[n][3]);
            p1[n][0] = cvt_relu_pk(acc1[n][0], acc1[n][1]);
            p1[n][1] = cvt_relu_pk(acc1[n][2], acc1[n][3]);
        }
        Blo0 = __builtin_bit_cast(h8, uint4v{p0[0][0], p0[0][1], p0[1][0], p0[1][1]});
        Bhi0 = __builtin_bit_cast(h8, uint4v{p0[2][0], p0[2][1], p0[3][0], p0[3][1]});
        Blo1 = __builtin_bit_cast(h8, uint4v{p1[0][0], p1[0][1], p1[1][0], p1[1][1]});
        Bhi1 = __builtin_bit_cast(h8, uint4v{p1[2][0], p1[2][1], p1[3][0], p1[3][1]});

        // ---- L3: 2 MFMAs per tile vs broadcast w3 rows; row 0 = dot + b3 ----
        f32x4 acc3_0, acc3_1;
        acc3_0 = __builtin_amdgcn_mfma_f32_16x16x32_f16(w3a[0], Blo0, c3,     0, 0, 0);
        acc3_1 = __builtin_amdgcn_mfma_f32_16x16x32_f16(w3a[0], Blo1, c3,     0, 0, 0);
        acc3_0 = __builtin_amdgcn_mfma_f32_16x16x32_f16(w3a[1], Bhi0, acc3_0, 0, 0, 0);
        acc3_1 = __builtin_amdgcn_mfma_f32_16x16x32_f16(w3a[1], Bhi1, acc3_1, 0, 0, 0);

        if (g == 0) {
            obase[(tt)     * 64 * Odim] = acc3_0[0];
            obase[(tt + 1) * 64 * Odim] = acc3_1[0];
        }
    }
}

extern "C" void kernel_launch(void* const* d_in, const int* in_sizes, int n_in,
                              void* d_out, int out_size, void* d_ws, size_t ws_size,
                              hipStream_t stream) {
    const float* x  = (const float*)d_in[0];
    const float* W0 = (const float*)d_in[1];
    const float* b0 = (const float*)d_in[2];
    const float* W1 = (const float*)d_in[3];
    const float* b1 = (const float*)d_in[4];
    const float* W2 = (const float*)d_in[5];
    const float* b2 = (const float*)d_in[6];
    const float* W3 = (const float*)d_in[7];
    const float* b3 = (const float*)d_in[8];
    float* out = (float*)d_out;
    char* ws = (char*)d_ws;   // needs 64*21504 = 1.38 MB

    prep_kernel<<<dim3(Odim), dim3(1024), 0, stream>>>(W0, b0, W1, b1, W2, b2, W3, ws);
    towers_kernel<<<dim3(Odim * BPT), dim3(256), 0, stream>>>(x, ws, b3, out);
}

// Round 13
// 33.001 us; speedup vs baseline: 7.1333x; 1.0307x over previous
//
#include <hip/hip_runtime.h>

// DividedModel: 64 towers of Dense(32,64)+ReLU -> 64x64+ReLU -> 64x64+ReLU -> 64x1.
// R12: R11 (f16, prep-image + global_load_lds staging, 2-tile ILP, pi-trick,
// bias-in-C, L3-as-MFMA, early x prefetch) with BPT 16 -> 8: 512 blocks ==
// exactly one residency round (2 blocks/CU x 256 CU), so the per-block fixed
// cost (DMA drain + frag hoist) is paid once. Prep widened to 256 blocks x
// 256 thr (4 blocks/tower) so it runs chip-wide and HBM-bound (~1.5us).

typedef float  f32x4 __attribute__((ext_vector_type(4)));
typedef _Float16 h8  __attribute__((ext_vector_type(8)));
typedef unsigned int uint4v __attribute__((ext_vector_type(4)));

static constexpr int Bsz  = 16384;
static constexpr int Idim = 32;
static constexpr int Odim = 64;
static constexpr int BPT  = 8;                     // blocks per tower -> 512 blocks total
static constexpr int ROWTILES = (Bsz / 64) / BPT;  // 32 tiles of 64 rows per block

// per-tower LDS image layout (bytes):
//   [0,4096)      ushort Wt0[64*32]   Wt0[h*32 + (i^swz0)]
//   [4096,12288)  ushort Wt1[64*64]   Wt1[h*64 + (S^swz1)]
//   [12288,20480) ushort Wt2[64*64]
//   [20480,20608) ushort w3s[64]      w3s[S]
//   [20608,21376) float  bs[192]      b0|b1|b2
//   [21376,21504) pad
static constexpr int IMG = 21504;                  // 21 chunks x 1024B

#define GLD16(gp, lp) __builtin_amdgcn_global_load_lds( \
    (const __attribute__((address_space(1))) void*)(gp), \
    (__attribute__((address_space(3))) void*)(lp), 16, 0, 0)

__device__ __forceinline__ unsigned short f2h(float f) {   // RNE f32->f16 (staging)
    _Float16 h = (_Float16)f;
    return __builtin_bit_cast(unsigned short, h);
}

__device__ __forceinline__ unsigned cvt_relu_pk(float lo, float hi) {
    // pack 2 f32 -> 2 f16 (RTZ), then packed ReLU: one v_pk_max_f16
    unsigned v = __builtin_bit_cast(unsigned, __builtin_amdgcn_cvt_pkrtz(lo, hi));
    unsigned r;
    asm("v_pk_max_f16 %0, %1, 0" : "=v"(r) : "v"(v));
    return r;
}

__device__ __forceinline__ unsigned cvt_pk2(float lo, float hi) {  // no relu (inputs)
    return __builtin_bit_cast(unsigned, __builtin_amdgcn_cvt_pkrtz(lo, hi));
}

// pi permutation: k-slot S for input-hidden index `in` (0..63).
// in_h(S) = 32*(S>>5) + 16*((S&7)>>2) + 4*((S>>3)&3) + (S&3).
__device__ __forceinline__ int pi_slot(int in) {
    return 32 * (in >> 5) + 8 * ((in >> 2) & 3) + 4 * ((in >> 4) & 1) + (in & 3);
}

// ---------------- prep: build per-tower LDS images in d_ws (chip-wide) ----------------
// grid = 64 towers x 4 quarter-blocks, 256 threads each.
__global__ __launch_bounds__(256) void prep_kernel(
    const float* __restrict__ W0, const float* __restrict__ b0,
    const float* __restrict__ W1, const float* __restrict__ b1,
    const float* __restrict__ W2, const float* __restrict__ b2,
    const float* __restrict__ W3, char* __restrict__ ws)
{
    const int o = blockIdx.x >> 2, q = blockIdx.x & 3, tid = threadIdx.x;
    char* img = ws + o * IMG;
    unsigned short* Wt0 = (unsigned short*)img;
    unsigned short* Wt1 = (unsigned short*)(img + 4096);
    unsigned short* Wt2 = (unsigned short*)(img + 12288);
    unsigned short* w3s = (unsigned short*)(img + 20480);
    float*          bsf = (float*)(img + 20608);

    {   // W1/W2: 1024 f32x4 chunks; this block handles q*256 + tid
        int f = q * 256 + tid;
        f32x4 v1 = *(const f32x4*)&W1[o * 4096 + f * 4];
        f32x4 v2 = *(const f32x4*)&W2[o * 4096 + f * 4];
        int in = (f * 4) >> 6;
        int h0 = (f * 4) & 63;
        int S  = pi_slot(in);
#pragma unroll
        for (int j = 0; j < 4; ++j) {
            int h = h0 + j;
            int cw = S ^ ((((h >> 2) ^ h) & 7) << 3);
            Wt1[h * 64 + cw] = f2h(v1[j]);
            Wt2[h * 64 + cw] = f2h(v2[j]);
        }
    }
    if (q < 2) {   // W0: 512 f32x4 chunks; blocks q=0,1
        int f = q * 256 + tid;
        f32x4 v = *(const f32x4*)&W0[o * 2048 + f * 4];
        int i  = (f * 4) >> 6;
        int h0 = (f * 4) & 63;
#pragma unroll
        for (int j = 0; j < 4; ++j) {
            int h = h0 + j;
            Wt0[h * 32 + (i ^ ((((h >> 2) ^ h) & 3) << 3))] = f2h(v[j]);
        }
    }
    if (q == 3 && tid < 64) {
        w3s[pi_slot(tid)] = f2h(W3[o * 64 + tid]);
        bsf[tid]       = b0[o * 64 + tid];
        bsf[64 + tid]  = b1[o * 64 + tid];
        bsf[128 + tid] = b2[o * 64 + tid];
    }
}

// ---------------- main: DMA-stage image, then 2-tile-ILP loop ----------------
__global__ __launch_bounds__(256, 2) void towers_kernel(
    const float* __restrict__ x, const char* __restrict__ ws,
    const float* __restrict__ b3, float* __restrict__ out)
{
    __shared__ __align__(16) char SH[IMG];

    const int tid  = threadIdx.x;
    const int o    = blockIdx.x / BPT;
    const int slot = blockIdx.x % BPT;
    const int l = tid & 63, w = tid >> 6;
    const int c = l & 15,  g = l >> 4;   // c: batch col; g: k-group / D row-group

    // ---- first x prefetch BEFORE staging: overlaps with image DMA ----
    const float* xbase = x + (slot * ROWTILES * 64 + w * 16 + c) * Idim + g * 8;
    f32x4 nxa0 = *(const f32x4*)(xbase);
    f32x4 nxb0 = *(const f32x4*)(xbase + 4);
    f32x4 nxa1 = *(const f32x4*)(xbase + 2048);
    f32x4 nxb1 = *(const f32x4*)(xbase + 2052);

    // ---- stage the tower image: 21 async 1KB chunks, waves round-robin ----
    {
        const char* img = ws + o * IMG;
#pragma unroll
        for (int ch = 0; ch < 6; ++ch) {
            int k = ch * 4 + w;
            if (k < 21)
                GLD16(img + k * 1024 + l * 16, SH + k * 1024);
        }
    }
    __syncthreads();

    const unsigned short* Wt0 = (const unsigned short*)SH;
    const unsigned short* Wt1 = (const unsigned short*)(SH + 4096);
    const unsigned short* w3s = (const unsigned short*)(SH + 20480);
    const float*          bsf = (const float*)(SH + 20608);

    // ---- persistent weight frags: W0 (16), W1 (32), w3 (8) ----
    h8 wf0[4], wf1f[4][2];
#pragma unroll
    for (int n = 0; n < 4; ++n) {
        int h = n * 16 + c;
        wf0[n] = *(const h8*)&Wt0[h * 32 + ((g * 8) ^ ((((h >> 2) ^ h) & 3) << 3))];
        int key = ((h >> 2) ^ h) & 7;
#pragma unroll
        for (int s = 0; s < 2; ++s)
            wf1f[n][s] = *(const h8*)&Wt1[h * 64 + ((s * 32 + g * 8) ^ (key << 3))];
    }
    h8 w3a[2];
    w3a[0] = *(const h8*)&w3s[g * 8];
    w3a[1] = *(const h8*)&w3s[32 + g * 8];

    // ---- W2 frag BYTE offsets into SH, precomputed (laundered per use) ----
    int off2[4][2];
#pragma unroll
    for (int n = 0; n < 4; ++n) {
        int h = n * 16 + c;
        int key = ((h >> 2) ^ h) & 7;
#pragma unroll
        for (int s = 0; s < 2; ++s)
            off2[n][s] = 12288 + 2 * (h * 64 + ((s * 32 + g * 8) ^ (key << 3)));
    }

    // ---- bias C-frags: element r of chunk n is hidden 16n+4g+r ----
    f32x4 b0f[4], b1f[4], b2f[4];
#pragma unroll
    for (int n = 0; n < 4; ++n) {
        b0f[n] = *(const f32x4*)&bsf[      n * 16 + g * 4];
        b1f[n] = *(const f32x4*)&bsf[ 64 + n * 16 + g * 4];
        b2f[n] = *(const f32x4*)&bsf[128 + n * 16 + g * 4];
    }
    f32x4 c3 = {0.f, 0.f, 0.f, 0.f};
    if (g == 0) c3[0] = b3[o];                // b3 lands on D row 0 only

    float* obase = out + (slot * ROWTILES * 64 + w * 16 + c) * Odim + o;

    for (int tt = 0; tt < ROWTILES; tt += 2) {
        f32x4 xa0 = nxa0, xb0 = nxb0, xa1 = nxa1, xb1 = nxb1;
        if (tt + 2 < ROWTILES) {              // prefetch next pair
            const float* np = xbase + (tt + 2) * 2048;
            nxa0 = *(const f32x4*)(np);
            nxb0 = *(const f32x4*)(np + 4);
            nxa1 = *(const f32x4*)(np + 2048);
            nxb1 = *(const f32x4*)(np + 2052);
        }

        // ---- L0 B-frags from x (cvt only, no relu) ----
        uint4v xd0, xd1;
        xd0.x = cvt_pk2(xa0[0], xa0[1]); xd0.y = cvt_pk2(xa0[2], xa0[3]);
        xd0.z = cvt_pk2(xb0[0], xb0[1]); xd0.w = cvt_pk2(xb0[2], xb0[3]);
        xd1.x = cvt_pk2(xa1[0], xa1[1]); xd1.y = cvt_pk2(xa1[2], xa1[3]);
        xd1.z = cvt_pk2(xb1[0], xb1[1]); xd1.w = cvt_pk2(xb1[2], xb1[3]);
        h8 a0_0 = __builtin_bit_cast(h8, xd0);
        h8 a0_1 = __builtin_bit_cast(h8, xd1);

        f32x4 acc0[4], acc1[4];
#pragma unroll
        for (int n = 0; n < 4; ++n) {
            acc0[n] = __builtin_amdgcn_mfma_f32_16x16x32_f16(wf0[n], a0_0, b0f[n], 0, 0, 0);
            acc1[n] = __builtin_amdgcn_mfma_f32_16x16x32_f16(wf0[n], a0_1, b0f[n], 0, 0, 0);
        }

        // ---- cvt+relu pack (lane-local thanks to pi staging) ----
        unsigned p0[4][2], p1[4][2];
#pragma unroll
        for (int n = 0; n < 4; ++n) {
            p0[n][0] = cvt_relu_pk(acc0[n][0], acc0[n][1]);
            p0[n][1] = cvt_relu_pk(acc0[n][2], acc0[n][3]);
            p1[n][0] = cvt_relu_pk(acc1[n][0], acc1[n][1]);
            p1[n][1] = cvt_relu_pk(acc1[n][2], acc1[n][3]);
        }
        h8 Blo0 = __builtin_bit_cast(h8, uint4v{p0[0][0], p0[0][1], p0[1][0], p0[1][1]});
        h8 Bhi0 = __builtin_bit_cast(h8, uint4v{p0[2][0], p0[2][1], p0[3][0], p0[3][1]});
        h8 Blo1 = __builtin_bit_cast(h8, uint4v{p1[0][0], p1[0][1], p1[1][0], p1[1][1]});
        h8 Bhi1 = __builtin_bit_cast(h8, uint4v{p1[2][0], p1[2][1], p1[3][0], p1[3][1]});

        // ---- L1 (weights in regs) ----
#pragma unroll
        for (int n = 0; n < 4; ++n) {
            acc0[n] = __builtin_amdgcn_mfma_f32_16x16x32_f16(wf1f[n][0], Blo0, b1f[n], 0, 0, 0);
            acc1[n] = __builtin_amdgcn_mfma_f32_16x16x32_f16(wf1f[n][0], Blo1, b1f[n], 0, 0, 0);
            acc0[n] = __builtin_amdgcn_mfma_f32_16x16x32_f16(wf1f[n][1], Bhi0, acc0[n], 0, 0, 0);
            acc1[n] = __builtin_amdgcn_mfma_f32_16x16x32_f16(wf1f[n][1], Bhi1, acc1[n], 0, 0, 0);
        }
#pragma unroll
        for (int n = 0; n < 4; ++n) {
            p0[n][0] = cvt_relu_pk(acc0[n][0], acc0[n][1]);
            p0[n][1] = cvt_relu_pk(acc0[n][2], acc0[n][3]);
            p1[n][0] = cvt_relu_pk(acc1[n][0], acc1[n][1]);
            p1[n][1] = cvt_relu_pk(acc1[n][2], acc1[n][3]);
        }
        Blo0 = __builtin_bit_cast(h8, uint4v{p0[0][0], p0[0][1], p0[1][0], p0[1][1]});
        Bhi0 = __builtin_bit_cast(h8, uint4v{p0[2][0], p0[2][1], p0[3][0], p0[3][1]});
        Blo1 = __builtin_bit_cast(h8, uint4v{p1[0][0], p1[0][1], p1[1][0], p1[1][1]});
        Bhi1 = __builtin_bit_cast(h8, uint4v{p1[2][0], p1[2][1], p1[3][0], p1[3][1]});

        // ---- L2: W2 frags from LDS (shared by both chains; laundered offsets) ----
        {
            const char* base = (const char*)SH;
            h8 w2[4];
#pragma unroll
            for (int n = 0; n < 4; ++n) {
                int a = off2[n][0];
                asm("" : "+v"(a));             // 1 v_mov; blocks LICM of the read
                w2[n] = *(const h8*)(base + a);
            }
#pragma unroll
            for (int n = 0; n < 4; ++n) {
                acc0[n] = __builtin_amdgcn_mfma_f32_16x16x32_f16(w2[n], Blo0, b2f[n], 0, 0, 0);
                acc1[n] = __builtin_amdgcn_mfma_f32_16x16x32_f16(w2[n], Blo1, b2f[n], 0, 0, 0);
            }
#pragma unroll
            for (int n = 0; n < 4; ++n) {
                int a = off2[n][1];
                asm("" : "+v"(a));
                w2[n] = *(const h8*)(base + a);
            }
#pragma unroll
            for (int n = 0; n < 4; ++n) {
                acc0[n] = __builtin_amdgcn_mfma_f32_16x16x32_f16(w2[n], Bhi0, acc0[n], 0, 0, 0);
                acc1[n] = __builtin_amdgcn_mfma_f32_16x16x32_f16(w2[n], Bhi1, acc1[n], 0, 0, 0);
            }
        }
#pragma unroll
        for (int n = 0; n < 4; ++n) {
            p0[n][0] = cvt_relu_pk(acc0[n][0], acc0[n][1]);
            p0[n][1] = cvt_relu_pk(acc0[n][2], acc0[n][3]);
            p1[n][0] = cvt_relu_pk(acc1[n][0], acc1[n][1]);
            p1[n][1] = cvt_relu_pk(acc1[n][2], acc1[n][3]);
        }
        Blo0 = __builtin_bit_cast(h8, uint4v{p0[0][0], p0[0][1], p0[1][0], p0[1][1]});
        Bhi0 = __builtin_bit_cast(h8, uint4v{p0[2][0], p0[2][1], p0[3][0], p0[3][1]});
        Blo1 = __builtin_bit_cast(h8, uint4v{p1[0][0], p1[0][1], p1[1][0], p1[1][1]});
        Bhi1 = __builtin_bit_cast(h8, uint4v{p1[2][0], p1[2][1], p1[3][0], p1[3][1]});

        // ---- L3: 2 MFMAs per tile vs broadcast w3 rows; row 0 = dot + b3 ----
        f32x4 acc3_0, acc3_1;
        acc3_0 = __builtin_amdgcn_mfma_f32_16x16x32_f16(w3a[0], Blo0, c3,     0, 0, 0);
        acc3_1 = __builtin_amdgcn_mfma_f32_16x16x32_f16(w3a[0], Blo1, c3,     0, 0, 0);
        acc3_0 = __builtin_amdgcn_mfma_f32_16x16x32_f16(w3a[1], Bhi0, acc3_0, 0, 0, 0);
        acc3_1 = __builtin_amdgcn_mfma_f32_16x16x32_f16(w3a[1], Bhi1, acc3_1, 0, 0, 0);

        if (g == 0) {
            obase[(tt)     * 64 * Odim] = acc3_0[0];
            obase[(tt + 1) * 64 * Odim] = acc3_1[0];
        }
    }
}

extern "C" void kernel_launch(void* const* d_in, const int* in_sizes, int n_in,
                              void* d_out, int out_size, void* d_ws, size_t ws_size,
                              hipStream_t stream) {
    const float* x  = (const float*)d_in[0];
    const float* W0 = (const float*)d_in[1];
    const float* b0 = (const float*)d_in[2];
    const float* W1 = (const float*)d_in[3];
    const float* b1 = (const float*)d_in[4];
    const float* W2 = (const float*)d_in[5];
    const float* b2 = (const float*)d_in[6];
    const float* W3 = (const float*)d_in[7];
    const float* b3 = (const float*)d_in[8];
    float* out = (float*)d_out;
    char* ws = (char*)d_ws;   // needs 64*21504 = 1.38 MB

    prep_kernel<<<dim3(Odim * 4), dim3(256), 0, stream>>>(W0, b0, W1, b1, W2, b2, W3, ws);
    towers_kernel<<<dim3(Odim * BPT), dim3(256), 0, stream>>>(x, ws, b3, out);
}

// Round 14
// 30.887 us; speedup vs baseline: 7.6214x; 1.0684x over previous
//
#include <hip/hip_runtime.h>

// DividedModel: 64 towers of Dense(32,64)+ReLU -> 64x64+ReLU -> 64x64+ReLU -> 64x1.
// R13: R12 (f16, prep-image + global_load_lds staging, pi-trick, bias-in-C,
// L3-as-MFMA, BPT=8 single-round) + (a) 4-tile ILP (8 iters x 4 independent
// chains; W2 LDS reads amortized 4x) and (b) x pre-converted f32->f16 in prep
// (L0 cvt ops vanish; x regs and fetch bytes halve).

typedef float  f32x4 __attribute__((ext_vector_type(4)));
typedef _Float16 h8  __attribute__((ext_vector_type(8)));
typedef unsigned int uint2v __attribute__((ext_vector_type(2)));
typedef unsigned int uint4v __attribute__((ext_vector_type(4)));

static constexpr int Bsz  = 16384;
static constexpr int Idim = 32;
static constexpr int Odim = 64;
static constexpr int BPT  = 8;                     // 512 blocks = one residency round
static constexpr int ROWTILES = (Bsz / 64) / BPT;  // 32 tiles of 64 rows per block
static constexpr int TT = 4;                       // tiles per iteration (ILP depth)

// per-tower LDS image layout (bytes):
//   [0,4096)      ushort Wt0[64*32]   Wt0[h*32 + (i^swz0)]
//   [4096,12288)  ushort Wt1[64*64]   Wt1[h*64 + (S^swz1)]
//   [12288,20480) ushort Wt2[64*64]
//   [20480,20608) ushort w3s[64]      w3s[S]
//   [20608,21376) float  bs[192]      b0|b1|b2
//   [21376,21504) pad
static constexpr int IMG = 21504;                  // 21 chunks x 1024B
static constexpr int XH_OFF = 64 * IMG;            // f16 copy of x: 1 MB at ws+XH_OFF

#define GLD16(gp, lp) __builtin_amdgcn_global_load_lds( \
    (const __attribute__((address_space(1))) void*)(gp), \
    (__attribute__((address_space(3))) void*)(lp), 16, 0, 0)

__device__ __forceinline__ unsigned short f2h(float f) {   // RNE f32->f16 (staging)
    _Float16 h = (_Float16)f;
    return __builtin_bit_cast(unsigned short, h);
}

__device__ __forceinline__ unsigned cvt_relu_pk(float lo, float hi) {
    // pack 2 f32 -> 2 f16 (RTZ), then packed ReLU: one v_pk_max_f16
    unsigned v = __builtin_bit_cast(unsigned, __builtin_amdgcn_cvt_pkrtz(lo, hi));
    unsigned r;
    asm("v_pk_max_f16 %0, %1, 0" : "=v"(r) : "v"(v));
    return r;
}

// pi permutation: k-slot S for input-hidden index `in` (0..63).
// in_h(S) = 32*(S>>5) + 16*((S&7)>>2) + 4*((S>>3)&3) + (S&3).
__device__ __forceinline__ int pi_slot(int in) {
    return 32 * (in >> 5) + 8 * ((in >> 2) & 3) + 4 * ((in >> 4) & 1) + (in & 3);
}

// ---------------- prep: weight images + x f16 copy (chip-wide) ----------------
// blocks 0..255: weights (o = b>>2, quarter q = b&3); blocks 256..767: x convert.
__global__ __launch_bounds__(256) void prep_kernel(
    const float* __restrict__ x,
    const float* __restrict__ W0, const float* __restrict__ b0,
    const float* __restrict__ W1, const float* __restrict__ b1,
    const float* __restrict__ W2, const float* __restrict__ b2,
    const float* __restrict__ W3, char* __restrict__ ws)
{
    const int tid = threadIdx.x;
    if (blockIdx.x >= 256) {                 // ---- x: f32 -> f16, 1 f32x4/thread ----
        int idx = (blockIdx.x - 256) * 256 + tid;      // 0..131071 chunks of 4
        f32x4 v = *(const f32x4*)&x[idx * 4];
        uint2v d;
        d.x = (unsigned)f2h(v[0]) | ((unsigned)f2h(v[1]) << 16);
        d.y = (unsigned)f2h(v[2]) | ((unsigned)f2h(v[3]) << 16);
        *(uint2v*)(ws + XH_OFF + idx * 8) = d;
        return;
    }
    const int o = blockIdx.x >> 2, q = blockIdx.x & 3;
    char* img = ws + o * IMG;
    unsigned short* Wt0 = (unsigned short*)img;
    unsigned short* Wt1 = (unsigned short*)(img + 4096);
    unsigned short* Wt2 = (unsigned short*)(img + 12288);
    unsigned short* w3s = (unsigned short*)(img + 20480);
    float*          bsf = (float*)(img + 20608);

    {   // W1/W2: 1024 f32x4 chunks; this block handles q*256 + tid
        int f = q * 256 + tid;
        f32x4 v1 = *(const f32x4*)&W1[o * 4096 + f * 4];
        f32x4 v2 = *(const f32x4*)&W2[o * 4096 + f * 4];
        int in = (f * 4) >> 6;
        int h0 = (f * 4) & 63;
        int S  = pi_slot(in);
#pragma unroll
        for (int j = 0; j < 4; ++j) {
            int h = h0 + j;
            int cw = S ^ ((((h >> 2) ^ h) & 7) << 3);
            Wt1[h * 64 + cw] = f2h(v1[j]);
            Wt2[h * 64 + cw] = f2h(v2[j]);
        }
    }
    if (q < 2) {   // W0: 512 f32x4 chunks; blocks q=0,1
        int f = q * 256 + tid;
        f32x4 v = *(const f32x4*)&W0[o * 2048 + f * 4];
        int i  = (f * 4) >> 6;
        int h0 = (f * 4) & 63;
#pragma unroll
        for (int j = 0; j < 4; ++j) {
            int h = h0 + j;
            Wt0[h * 32 + (i ^ ((((h >> 2) ^ h) & 3) << 3))] = f2h(v[j]);
        }
    }
    if (q == 3 && tid < 64) {
        w3s[pi_slot(tid)] = f2h(W3[o * 64 + tid]);
        bsf[tid]       = b0[o * 64 + tid];
        bsf[64 + tid]  = b1[o * 64 + tid];
        bsf[128 + tid] = b2[o * 64 + tid];
    }
}

// ---------------- main: DMA-stage image, then 4-tile-ILP loop ----------------
__global__ __launch_bounds__(256, 2) void towers_kernel(
    const char* __restrict__ ws, const float* __restrict__ b3,
    float* __restrict__ out)
{
    __shared__ __align__(16) char SH[IMG];

    const int tid  = threadIdx.x;
    const int o    = blockIdx.x / BPT;
    const int slot = blockIdx.x % BPT;
    const int l = tid & 63, w = tid >> 6;
    const int c = l & 15,  g = l >> 4;   // c: batch col; g: k-group / D row-group

    // ---- first x prefetch BEFORE staging: overlaps with image DMA ----
    const _Float16* xh = (const _Float16*)(ws + XH_OFF);
    const _Float16* xbase = xh + (slot * ROWTILES * 64 + w * 16 + c) * Idim + g * 8;
    h8 nxv[TT];
#pragma unroll
    for (int k = 0; k < TT; ++k)
        nxv[k] = *(const h8*)(xbase + k * 2048);   // 64 rows x 32 = 2048 f16 per tile

    // ---- stage the tower image: 21 async 1KB chunks, waves round-robin ----
    {
        const char* img = ws + o * IMG;
#pragma unroll
        for (int ch = 0; ch < 6; ++ch) {
            int k = ch * 4 + w;
            if (k < 21)
                GLD16(img + k * 1024 + l * 16, SH + k * 1024);
        }
    }
    __syncthreads();

    const unsigned short* Wt0 = (const unsigned short*)SH;
    const unsigned short* Wt1 = (const unsigned short*)(SH + 4096);
    const unsigned short* w3s = (const unsigned short*)(SH + 20480);
    const float*          bsf = (const float*)(SH + 20608);

    // ---- persistent weight frags: W0 (16), W1 (32), w3 (8) ----
    h8 wf0[4], wf1f[4][2];
#pragma unroll
    for (int n = 0; n < 4; ++n) {
        int h = n * 16 + c;
        wf0[n] = *(const h8*)&Wt0[h * 32 + ((g * 8) ^ ((((h >> 2) ^ h) & 3) << 3))];
        int key = ((h >> 2) ^ h) & 7;
#pragma unroll
        for (int s = 0; s < 2; ++s)
            wf1f[n][s] = *(const h8*)&Wt1[h * 64 + ((s * 32 + g * 8) ^ (key << 3))];
    }
    h8 w3a[2];
    w3a[0] = *(const h8*)&w3s[g * 8];
    w3a[1] = *(const h8*)&w3s[32 + g * 8];

    // ---- W2 frag BYTE offsets into SH, precomputed (laundered per use) ----
    int off2[4][2];
#pragma unroll
    for (int n = 0; n < 4; ++n) {
        int h = n * 16 + c;
        int key = ((h >> 2) ^ h) & 7;
#pragma unroll
        for (int s = 0; s < 2; ++s)
            off2[n][s] = 12288 + 2 * (h * 64 + ((s * 32 + g * 8) ^ (key << 3)));
    }

    // ---- bias C-frags: element r of chunk n is hidden 16n+4g+r ----
    f32x4 b0f[4], b1f[4], b2f[4];
#pragma unroll
    for (int n = 0; n < 4; ++n) {
        b0f[n] = *(const f32x4*)&bsf[      n * 16 + g * 4];
        b1f[n] = *(const f32x4*)&bsf[ 64 + n * 16 + g * 4];
        b2f[n] = *(const f32x4*)&bsf[128 + n * 16 + g * 4];
    }
    f32x4 c3 = {0.f, 0.f, 0.f, 0.f};
    if (g == 0) c3[0] = b3[o];                // b3 lands on D row 0 only

    float* obase = out + (slot * ROWTILES * 64 + w * 16 + c) * Odim + o;

    for (int tt = 0; tt < ROWTILES; tt += TT) {
        h8 xv[TT];
#pragma unroll
        for (int k = 0; k < TT; ++k) xv[k] = nxv[k];
        if (tt + TT < ROWTILES) {             // prefetch next group
#pragma unroll
            for (int k = 0; k < TT; ++k)
                nxv[k] = *(const h8*)(xbase + (tt + TT + k) * 2048);
        }

        // ---- L0: x already f16 -> straight into MFMA ----
        f32x4 acc[TT][4];
#pragma unroll
        for (int n = 0; n < 4; ++n)
#pragma unroll
            for (int k = 0; k < TT; ++k)
                acc[k][n] = __builtin_amdgcn_mfma_f32_16x16x32_f16(wf0[n], xv[k], b0f[n], 0, 0, 0);

        // ---- cvt+relu pack (lane-local thanks to pi staging) ----
        h8 blo[TT], bhi[TT];
#pragma unroll
        for (int k = 0; k < TT; ++k) {
            uint4v lo, hi;
            lo.x = cvt_relu_pk(acc[k][0][0], acc[k][0][1]);
            lo.y = cvt_relu_pk(acc[k][0][2], acc[k][0][3]);
            lo.z = cvt_relu_pk(acc[k][1][0], acc[k][1][1]);
            lo.w = cvt_relu_pk(acc[k][1][2], acc[k][1][3]);
            hi.x = cvt_relu_pk(acc[k][2][0], acc[k][2][1]);
            hi.y = cvt_relu_pk(acc[k][2][2], acc[k][2][3]);
            hi.z = cvt_relu_pk(acc[k][3][0], acc[k][3][1]);
            hi.w = cvt_relu_pk(acc[k][3][2], acc[k][3][3]);
            blo[k] = __builtin_bit_cast(h8, lo);
            bhi[k] = __builtin_bit_cast(h8, hi);
        }

        // ---- L1 (weights in regs) ----
#pragma unroll
        for (int n = 0; n < 4; ++n)
#pragma unroll
            for (int k = 0; k < TT; ++k) {
                acc[k][n] = __builtin_amdgcn_mfma_f32_16x16x32_f16(wf1f[n][0], blo[k], b1f[n], 0, 0, 0);
                acc[k][n] = __builtin_amdgcn_mfma_f32_16x16x32_f16(wf1f[n][1], bhi[k], acc[k][n], 0, 0, 0);
            }
#pragma unroll
        for (int k = 0; k < TT; ++k) {
            uint4v lo, hi;
            lo.x = cvt_relu_pk(acc[k][0][0], acc[k][0][1]);
            lo.y = cvt_relu_pk(acc[k][0][2], acc[k][0][3]);
            lo.z = cvt_relu_pk(acc[k][1][0], acc[k][1][1]);
            lo.w = cvt_relu_pk(acc[k][1][2], acc[k][1][3]);
            hi.x = cvt_relu_pk(acc[k][2][0], acc[k][2][1]);
            hi.y = cvt_relu_pk(acc[k][2][2], acc[k][2][3]);
            hi.z = cvt_relu_pk(acc[k][3][0], acc[k][3][1]);
            hi.w = cvt_relu_pk(acc[k][3][2], acc[k][3][3]);
            blo[k] = __builtin_bit_cast(h8, lo);
            bhi[k] = __builtin_bit_cast(h8, hi);
        }

        // ---- L2: W2 frags from LDS (shared by all 4 chains; laundered offsets) ----
        {
            const char* base = (const char*)SH;
            h8 w2[4];
#pragma unroll
            for (int n = 0; n < 4; ++n) {
                int a = off2[n][0];
                asm("" : "+v"(a));             // 1 v_mov; blocks LICM of the read
                w2[n] = *(const h8*)(base + a);
            }
#pragma unroll
            for (int n = 0; n < 4; ++n)
#pragma unroll
                for (int k = 0; k < TT; ++k)
                    acc[k][n] = __builtin_amdgcn_mfma_f32_16x16x32_f16(w2[n], blo[k], b2f[n], 0, 0, 0);
#pragma unroll
            for (int n = 0; n < 4; ++n) {
                int a = off2[n][1];
                asm("" : "+v"(a));
                w2[n] = *(const h8*)(base + a);
            }
#pragma unroll
            for (int n = 0; n < 4; ++n)
#pragma unroll
                for (int k = 0; k < TT; ++k)
                    acc[k][n] = __builtin_amdgcn_mfma_f32_16x16x32_f16(w2[n], bhi[k], acc[k][n], 0, 0, 0);
        }
#pragma unroll
        for (int k = 0; k < TT; ++k) {
            uint4v lo, hi;
            lo.x = cvt_relu_pk(acc[k][0][0], acc[k][0][1]);
            lo.y = cvt_relu_pk(acc[k][0][2], acc[k][0][3]);
            lo.z = cvt_relu_pk(acc[k][1][0], acc[k][1][1]);
            lo.w = cvt_relu_pk(acc[k][1][2], acc[k][1][3]);
            hi.x = cvt_relu_pk(acc[k][2][0], acc[k][2][1]);
            hi.y = cvt_relu_pk(acc[k][2][2], acc[k][2][3]);
            hi.z = cvt_relu_pk(acc[k][3][0], acc[k][3][1]);
            hi.w = cvt_relu_pk(acc[k][3][2], acc[k][3][3]);
            blo[k] = __builtin_bit_cast(h8, lo);
            bhi[k] = __builtin_bit_cast(h8, hi);
        }

        // ---- L3: 2 chained MFMAs per tile vs broadcast w3 rows; row 0 = dot + b3 ----
#pragma unroll
        for (int k = 0; k < TT; ++k) {
            f32x4 a3;
            a3 = __builtin_amdgcn_mfma_f32_16x16x32_f16(w3a[0], blo[k], c3, 0, 0, 0);
            a3 = __builtin_amdgcn_mfma_f32_16x16x32_f16(w3a[1], bhi[k], a3, 0, 0, 0);
            if (g == 0)
                obase[(tt + k) * 64 * Odim] = a3[0];
        }
    }
}

extern "C" void kernel_launch(void* const* d_in, const int* in_sizes, int n_in,
                              void* d_out, int out_size, void* d_ws, size_t ws_size,
                              hipStream_t stream) {
    const float* x  = (const float*)d_in[0];
    const float* W0 = (const float*)d_in[1];
    const float* b0 = (const float*)d_in[2];
    const float* W1 = (const float*)d_in[3];
    const float* b1 = (const float*)d_in[4];
    const float* W2 = (const float*)d_in[5];
    const float* b2 = (const float*)d_in[6];
    const float* W3 = (const float*)d_in[7];
    const float* b3 = (const float*)d_in[8];
    float* out = (float*)d_out;
    char* ws = (char*)d_ws;   // needs 64*21504 + 1MB = 2.43 MB

    prep_kernel<<<dim3(256 + 512), dim3(256), 0, stream>>>(x, W0, b0, W1, b1, W2, b2, W3, ws);
    towers_kernel<<<dim3(Odim * BPT), dim3(256), 0, stream>>>(ws, b3, out);
}

// Round 15
// 29.436 us; speedup vs baseline: 7.9972x; 1.0493x over previous
//
#include <hip/hip_runtime.h>

// DividedModel: 64 towers of Dense(32,64)+ReLU -> 64x64+ReLU -> 64x64+ReLU -> 64x1.
// R14: R13 (f16, prep-image + global_load_lds staging, pi-trick, bias-in-C,
// L3-as-MFMA, BPT=8 single-round, 4-tile ILP, x pre-converted) with:
// (a) W2 hoisted to persistent registers -- ZERO memory ops in the main loop
//     (we're pinned at 2 waves/SIMD in the 129-256 reg band anyway; frugality
//     bought nothing, so spend the registers on removing lgkm stalls);
// (b) s_setprio(1) around MFMA clusters (T5; barrier-free loop => waves drift
//     out of phase => role diversity exists).

typedef float  f32x4 __attribute__((ext_vector_type(4)));
typedef _Float16 h8  __attribute__((ext_vector_type(8)));
typedef unsigned int uint2v __attribute__((ext_vector_type(2)));
typedef unsigned int uint4v __attribute__((ext_vector_type(4)));

static constexpr int Bsz  = 16384;
static constexpr int Idim = 32;
static constexpr int Odim = 64;
static constexpr int BPT  = 8;                     // 512 blocks = one residency round
static constexpr int ROWTILES = (Bsz / 64) / BPT;  // 32 tiles of 64 rows per block
static constexpr int TT = 4;                       // tiles per iteration (ILP depth)

// per-tower LDS image layout (bytes):
//   [0,4096)      ushort Wt0[64*32]   Wt0[h*32 + (i^swz0)]
//   [4096,12288)  ushort Wt1[64*64]   Wt1[h*64 + (S^swz1)]
//   [12288,20480) ushort Wt2[64*64]
//   [20480,20608) ushort w3s[64]      w3s[S]
//   [20608,21376) float  bs[192]      b0|b1|b2
//   [21376,21504) pad
static constexpr int IMG = 21504;                  // 21 chunks x 1024B
static constexpr int XH_OFF = 64 * IMG;            // f16 copy of x: 1 MB at ws+XH_OFF

#define GLD16(gp, lp) __builtin_amdgcn_global_load_lds( \
    (const __attribute__((address_space(1))) void*)(gp), \
    (__attribute__((address_space(3))) void*)(lp), 16, 0, 0)

__device__ __forceinline__ unsigned short f2h(float f) {   // RNE f32->f16 (staging)
    _Float16 h = (_Float16)f;
    return __builtin_bit_cast(unsigned short, h);
}

__device__ __forceinline__ unsigned cvt_relu_pk(float lo, float hi) {
    // pack 2 f32 -> 2 f16 (RTZ), then packed ReLU: one v_pk_max_f16
    unsigned v = __builtin_bit_cast(unsigned, __builtin_amdgcn_cvt_pkrtz(lo, hi));
    unsigned r;
    asm("v_pk_max_f16 %0, %1, 0" : "=v"(r) : "v"(v));
    return r;
}

// pi permutation: k-slot S for input-hidden index `in` (0..63).
// in_h(S) = 32*(S>>5) + 16*((S&7)>>2) + 4*((S>>3)&3) + (S&3).
__device__ __forceinline__ int pi_slot(int in) {
    return 32 * (in >> 5) + 8 * ((in >> 2) & 3) + 4 * ((in >> 4) & 1) + (in & 3);
}

// ---------------- prep: weight images + x f16 copy (chip-wide) ----------------
// blocks 0..255: weights (o = b>>2, quarter q = b&3); blocks 256..767: x convert.
__global__ __launch_bounds__(256) void prep_kernel(
    const float* __restrict__ x,
    const float* __restrict__ W0, const float* __restrict__ b0,
    const float* __restrict__ W1, const float* __restrict__ b1,
    const float* __restrict__ W2, const float* __restrict__ b2,
    const float* __restrict__ W3, char* __restrict__ ws)
{
    const int tid = threadIdx.x;
    if (blockIdx.x >= 256) {                 // ---- x: f32 -> f16, 1 f32x4/thread ----
        int idx = (blockIdx.x - 256) * 256 + tid;      // 0..131071 chunks of 4
        f32x4 v = *(const f32x4*)&x[idx * 4];
        uint2v d;
        d.x = (unsigned)f2h(v[0]) | ((unsigned)f2h(v[1]) << 16);
        d.y = (unsigned)f2h(v[2]) | ((unsigned)f2h(v[3]) << 16);
        *(uint2v*)(ws + XH_OFF + idx * 8) = d;
        return;
    }
    const int o = blockIdx.x >> 2, q = blockIdx.x & 3;
    char* img = ws + o * IMG;
    unsigned short* Wt0 = (unsigned short*)img;
    unsigned short* Wt1 = (unsigned short*)(img + 4096);
    unsigned short* Wt2 = (unsigned short*)(img + 12288);
    unsigned short* w3s = (unsigned short*)(img + 20480);
    float*          bsf = (float*)(img + 20608);

    {   // W1/W2: 1024 f32x4 chunks; this block handles q*256 + tid
        int f = q * 256 + tid;
        f32x4 v1 = *(const f32x4*)&W1[o * 4096 + f * 4];
        f32x4 v2 = *(const f32x4*)&W2[o * 4096 + f * 4];
        int in = (f * 4) >> 6;
        int h0 = (f * 4) & 63;
        int S  = pi_slot(in);
#pragma unroll
        for (int j = 0; j < 4; ++j) {
            int h = h0 + j;
            int cw = S ^ ((((h >> 2) ^ h) & 7) << 3);
            Wt1[h * 64 + cw] = f2h(v1[j]);
            Wt2[h * 64 + cw] = f2h(v2[j]);
        }
    }
    if (q < 2) {   // W0: 512 f32x4 chunks; blocks q=0,1
        int f = q * 256 + tid;
        f32x4 v = *(const f32x4*)&W0[o * 2048 + f * 4];
        int i  = (f * 4) >> 6;
        int h0 = (f * 4) & 63;
#pragma unroll
        for (int j = 0; j < 4; ++j) {
            int h = h0 + j;
            Wt0[h * 32 + (i ^ ((((h >> 2) ^ h) & 3) << 3))] = f2h(v[j]);
        }
    }
    if (q == 3 && tid < 64) {
        w3s[pi_slot(tid)] = f2h(W3[o * 64 + tid]);
        bsf[tid]       = b0[o * 64 + tid];
        bsf[64 + tid]  = b1[o * 64 + tid];
        bsf[128 + tid] = b2[o * 64 + tid];
    }
}

// ---------------- main: DMA-stage image, then 4-tile-ILP loop ----------------
__global__ __launch_bounds__(256, 2) void towers_kernel(
    const char* __restrict__ ws, const float* __restrict__ b3,
    float* __restrict__ out)
{
    __shared__ __align__(16) char SH[IMG];

    const int tid  = threadIdx.x;
    const int o    = blockIdx.x / BPT;
    const int slot = blockIdx.x % BPT;
    const int l = tid & 63, w = tid >> 6;
    const int c = l & 15,  g = l >> 4;   // c: batch col; g: k-group / D row-group

    // ---- first x prefetch BEFORE staging: overlaps with image DMA ----
    const _Float16* xh = (const _Float16*)(ws + XH_OFF);
    const _Float16* xbase = xh + (slot * ROWTILES * 64 + w * 16 + c) * Idim + g * 8;
    h8 nxv[TT];
#pragma unroll
    for (int k = 0; k < TT; ++k)
        nxv[k] = *(const h8*)(xbase + k * 2048);   // 64 rows x 32 = 2048 f16 per tile

    // ---- stage the tower image: 21 async 1KB chunks, waves round-robin ----
    {
        const char* img = ws + o * IMG;
#pragma unroll
        for (int ch = 0; ch < 6; ++ch) {
            int k = ch * 4 + w;
            if (k < 21)
                GLD16(img + k * 1024 + l * 16, SH + k * 1024);
        }
    }
    __syncthreads();

    const unsigned short* Wt0 = (const unsigned short*)SH;
    const unsigned short* Wt1 = (const unsigned short*)(SH + 4096);
    const unsigned short* Wt2 = (const unsigned short*)(SH + 12288);
    const unsigned short* w3s = (const unsigned short*)(SH + 20480);
    const float*          bsf = (const float*)(SH + 20608);

    // ---- persistent weight frags: W0 (16), W1 (32), W2 (32), w3 (8) ----
    h8 wf0[4], wf1f[4][2], wf2f[4][2];
#pragma unroll
    for (int n = 0; n < 4; ++n) {
        int h = n * 16 + c;
        wf0[n] = *(const h8*)&Wt0[h * 32 + ((g * 8) ^ ((((h >> 2) ^ h) & 3) << 3))];
        int key = ((h >> 2) ^ h) & 7;
#pragma unroll
        for (int s = 0; s < 2; ++s) {
            int col = (s * 32 + g * 8) ^ (key << 3);
            wf1f[n][s] = *(const h8*)&Wt1[h * 64 + col];
            wf2f[n][s] = *(const h8*)&Wt2[h * 64 + col];
        }
    }
    h8 w3a[2];
    w3a[0] = *(const h8*)&w3s[g * 8];
    w3a[1] = *(const h8*)&w3s[32 + g * 8];

    // ---- bias C-frags: element r of chunk n is hidden 16n+4g+r ----
    f32x4 b0f[4], b1f[4], b2f[4];
#pragma unroll
    for (int n = 0; n < 4; ++n) {
        b0f[n] = *(const f32x4*)&bsf[      n * 16 + g * 4];
        b1f[n] = *(const f32x4*)&bsf[ 64 + n * 16 + g * 4];
        b2f[n] = *(const f32x4*)&bsf[128 + n * 16 + g * 4];
    }
    f32x4 c3 = {0.f, 0.f, 0.f, 0.f};
    if (g == 0) c3[0] = b3[o];                // b3 lands on D row 0 only

    float* obase = out + (slot * ROWTILES * 64 + w * 16 + c) * Odim + o;

    for (int tt = 0; tt < ROWTILES; tt += TT) {
        h8 xv[TT];
#pragma unroll
        for (int k = 0; k < TT; ++k) xv[k] = nxv[k];
        if (tt + TT < ROWTILES) {             // prefetch next group
#pragma unroll
            for (int k = 0; k < TT; ++k)
                nxv[k] = *(const h8*)(xbase + (tt + TT + k) * 2048);
        }

        // ---- L0: x already f16 -> straight into MFMA ----
        f32x4 acc[TT][4];
        __builtin_amdgcn_s_setprio(1);
#pragma unroll
        for (int n = 0; n < 4; ++n)
#pragma unroll
            for (int k = 0; k < TT; ++k)
                acc[k][n] = __builtin_amdgcn_mfma_f32_16x16x32_f16(wf0[n], xv[k], b0f[n], 0, 0, 0);
        __builtin_amdgcn_s_setprio(0);

        // ---- cvt+relu pack (lane-local thanks to pi staging) ----
        h8 blo[TT], bhi[TT];
#pragma unroll
        for (int k = 0; k < TT; ++k) {
            uint4v lo, hi;
            lo.x = cvt_relu_pk(acc[k][0][0], acc[k][0][1]);
            lo.y = cvt_relu_pk(acc[k][0][2], acc[k][0][3]);
            lo.z = cvt_relu_pk(acc[k][1][0], acc[k][1][1]);
            lo.w = cvt_relu_pk(acc[k][1][2], acc[k][1][3]);
            hi.x = cvt_relu_pk(acc[k][2][0], acc[k][2][1]);
            hi.y = cvt_relu_pk(acc[k][2][2], acc[k][2][3]);
            hi.z = cvt_relu_pk(acc[k][3][0], acc[k][3][1]);
            hi.w = cvt_relu_pk(acc[k][3][2], acc[k][3][3]);
            blo[k] = __builtin_bit_cast(h8, lo);
            bhi[k] = __builtin_bit_cast(h8, hi);
        }

        // ---- L1 ----
        __builtin_amdgcn_s_setprio(1);
#pragma unroll
        for (int n = 0; n < 4; ++n)
#pragma unroll
            for (int k = 0; k < TT; ++k) {
                acc[k][n] = __builtin_amdgcn_mfma_f32_16x16x32_f16(wf1f[n][0], blo[k], b1f[n], 0, 0, 0);
                acc[k][n] = __builtin_amdgcn_mfma_f32_16x16x32_f16(wf1f[n][1], bhi[k], acc[k][n], 0, 0, 0);
            }
        __builtin_amdgcn_s_setprio(0);
#pragma unroll
        for (int k = 0; k < TT; ++k) {
            uint4v lo, hi;
            lo.x = cvt_relu_pk(acc[k][0][0], acc[k][0][1]);
            lo.y = cvt_relu_pk(acc[k][0][2], acc[k][0][3]);
            lo.z = cvt_relu_pk(acc[k][1][0], acc[k][1][1]);
            lo.w = cvt_relu_pk(acc[k][1][2], acc[k][1][3]);
            hi.x = cvt_relu_pk(acc[k][2][0], acc[k][2][1]);
            hi.y = cvt_relu_pk(acc[k][2][2], acc[k][2][3]);
            hi.z = cvt_relu_pk(acc[k][3][0], acc[k][3][1]);
            hi.w = cvt_relu_pk(acc[k][3][2], acc[k][3][3]);
            blo[k] = __builtin_bit_cast(h8, lo);
            bhi[k] = __builtin_bit_cast(h8, hi);
        }

        // ---- L2 (weights in regs now -- zero memory ops in loop) ----
        __builtin_amdgcn_s_setprio(1);
#pragma unroll
        for (int n = 0; n < 4; ++n)
#pragma unroll
            for (int k = 0; k < TT; ++k) {
                acc[k][n] = __builtin_amdgcn_mfma_f32_16x16x32_f16(wf2f[n][0], blo[k], b2f[n], 0, 0, 0);
                acc[k][n] = __builtin_amdgcn_mfma_f32_16x16x32_f16(wf2f[n][1], bhi[k], acc[k][n], 0, 0, 0);
            }
        __builtin_amdgcn_s_setprio(0);
#pragma unroll
        for (int k = 0; k < TT; ++k) {
            uint4v lo, hi;
            lo.x = cvt_relu_pk(acc[k][0][0], acc[k][0][1]);
            lo.y = cvt_relu_pk(acc[k][0][2], acc[k][0][3]);
            lo.z = cvt_relu_pk(acc[k][1][0], acc[k][1][1]);
            lo.w = cvt_relu_pk(acc[k][1][2], acc[k][1][3]);
            hi.x = cvt_relu_pk(acc[k][2][0], acc[k][2][1]);
            hi.y = cvt_relu_pk(acc[k][2][2], acc[k][2][3]);
            hi.z = cvt_relu_pk(acc[k][3][0], acc[k][3][1]);
            hi.w = cvt_relu_pk(acc[k][3][2], acc[k][3][3]);
            blo[k] = __builtin_bit_cast(h8, lo);
            bhi[k] = __builtin_bit_cast(h8, hi);
        }

        // ---- L3: 2 chained MFMAs per tile vs broadcast w3 rows; row 0 = dot + b3 ----
        __builtin_amdgcn_s_setprio(1);
        f32x4 a3[TT];
#pragma unroll
        for (int k = 0; k < TT; ++k) {
            a3[k] = __builtin_amdgcn_mfma_f32_16x16x32_f16(w3a[0], blo[k], c3, 0, 0, 0);
            a3[k] = __builtin_amdgcn_mfma_f32_16x16x32_f16(w3a[1], bhi[k], a3[k], 0, 0, 0);
        }
        __builtin_amdgcn_s_setprio(0);
#pragma unroll
        for (int k = 0; k < TT; ++k)
            if (g == 0)
                obase[(tt + k) * 64 * Odim] = a3[k][0];
    }
}

extern "C" void kernel_launch(void* const* d_in, const int* in_sizes, int n_in,
                              void* d_out, int out_size, void* d_ws, size_t ws_size,
                              hipStream_t stream) {
    const float* x  = (const float*)d_in[0];
    const float* W0 = (const float*)d_in[1];
    const float* b0 = (const float*)d_in[2];
    const float* W1 = (const float*)d_in[3];
    const float* b1 = (const float*)d_in[4];
    const float* W2 = (const float*)d_in[5];
    const float* b2 = (const float*)d_in[6];
    const float* W3 = (const float*)d_in[7];
    const float* b3 = (const float*)d_in[8];
    float* out = (float*)d_out;
    char* ws = (char*)d_ws;   // needs 64*21504 + 1MB = 2.43 MB

    prep_kernel<<<dim3(256 + 512), dim3(256), 0, stream>>>(x, W0, b0, W1, b1, W2, b2, W3, ws);
    towers_kernel<<<dim3(Odim * BPT), dim3(256), 0, stream>>>(ws, b3, out);
}